// Round 8
// baseline (1655.343 us; speedup 1.0000x reference)
//
#include <hip/hip_runtime.h>
#include <hip/hip_bf16.h>

// ---------------- helpers ----------------
__device__ __forceinline__ int sgnf(float v){ return (v>0.f)-(v<0.f); }
__device__ __forceinline__ ushort f2b(float f){ __hip_bfloat16 h = __float2bfloat16(f); return __builtin_bit_cast(ushort, h); }
__device__ __forceinline__ float  b2f(ushort u){ __hip_bfloat16 h = __builtin_bit_cast(__hip_bfloat16, u); return __bfloat162float(h); }
__device__ __forceinline__ float  tof(float v){ return v; }
__device__ __forceinline__ float  tof(ushort v){ return b2f(v); }

typedef short  s8v  __attribute__((ext_vector_type(8)));
typedef ushort us8  __attribute__((ext_vector_type(8)));
typedef float  f4v  __attribute__((ext_vector_type(4)));

// =====================================================================
// f32 tiled 3x3 conv, 4x4 outputs per thread (register tile).
// RELU=true: full conv + relu. RELU=false: K-split partial (raw, slab y).
// =====================================================================
template<int STRIDE, int TH, int TW, int CO_T, int CI_T, int NT, int P, bool RELU>
__global__ __launch_bounds__(NT) void conv3_t44(
    const float* __restrict__ in, const float* __restrict__ w, float* __restrict__ out,
    int N, int Ci, int Co, int Hi, int Wi, int Ho, int Wo, int ciLen)
{
    constexpr int NSP   = (TH/4)*(TW/4);
    constexpr int IT_H  = (TH-1)*STRIDE + 3;
    constexpr int IT_W  = (TW-1)*STRIDE + 3;
    constexpr int IN_ELEMS = CI_T*IT_H*IT_W;
    constexpr int W_ELEMS  = CI_T*CO_T*9;
    static_assert(NSP*CO_T == NT, "thread count mismatch");
    static_assert(IT_W <= P, "pitch too small");

    __shared__ __align__(16) float s_in[CI_T*IT_H*P];
    __shared__ __align__(16) float s_w[CI_T*CO_T*12];

    int bx = blockIdx.x;
    const int spxn = Wo/TW, spyn = Ho/TH, cog = Co/CO_T;
    const int sxb = bx % spxn; bx /= spxn;
    const int syb = bx % spyn; bx /= spyn;
    const int cg  = bx % cog;  const int n = bx / cog;
    const int tx0 = sxb*TW, ty0 = syb*TH, co0 = cg*CO_T;

    const int ciStart = RELU ? 0 : blockIdx.y * ciLen;
    const int ciEnd   = RELU ? Ci : ciStart + ciLen;
    if (!RELU) out += (size_t)blockIdx.y * N * Co * Ho * Wo;

    const int tid = threadIdx.x;
    const int sp  = tid % NSP;
    const int co  = tid / NSP;
    const int sy  = (sp / (TW/4)) * 4;
    const int sx  = (sp % (TW/4)) * 4;

    const int y_in0 = ty0*STRIDE - 1, x_in0 = tx0*STRIDE - 1;
    const float* in_n = in + (size_t)n*Ci*Hi*Wi;

    float acc[4][4];
    #pragma unroll
    for (int i=0;i<4;++i)
        #pragma unroll
        for (int j=0;j<4;++j) acc[i][j] = 0.f;

    for (int ci0 = ciStart; ci0 < ciEnd; ci0 += CI_T) {
        for (int idx = tid; idx < IN_ELEMS; idx += NT) {
            int ci  = idx / (IT_H*IT_W);
            int rem = idx - ci*(IT_H*IT_W);
            int iy  = rem / IT_W;
            int ix  = rem - iy*IT_W;
            int gy = y_in0 + iy, gx = x_in0 + ix;
            float v = 0.f;
            if ((unsigned)gy < (unsigned)Hi && (unsigned)gx < (unsigned)Wi)
                v = in_n[(size_t)(ci0+ci)*Hi*Wi + gy*Wi + gx];
            s_in[ci*(IT_H*P) + iy*P + ix] = v;
        }
        for (int idx = tid; idx < W_ELEMS; idx += NT) {
            int ci  = idx / (CO_T*9);
            int rem = idx - ci*(CO_T*9);
            int c   = rem / 9, k = rem - c*9;
            s_w[(ci*CO_T + c)*12 + k] = w[((size_t)(co0+c)*Ci + (ci0+ci))*9 + k];
        }
        __syncthreads();

        #pragma unroll
        for (int ci = 0; ci < CI_T; ++ci) {
            const float* wp = &s_w[(ci*CO_T + co)*12];
            float4 wa = *(const float4*)wp;
            float4 wb = *(const float4*)(wp+4);
            float w8  = wp[8];
            float wr[9] = {wa.x,wa.y,wa.z,wa.w, wb.x,wb.y,wb.z,wb.w, w8};
            const float* ip = &s_in[ci*(IT_H*P)];

            if constexpr (STRIDE == 1) {
                #pragma unroll
                for (int pr = 0; pr < 6; ++pr) {
                    const float* row = ip + (sy+pr)*P + sx;
                    float4 a = *(const float4*)row;
                    float2 b = *(const float2*)(row+4);
                    float e[6] = {a.x,a.y,a.z,a.w,b.x,b.y};
                    #pragma unroll
                    for (int ky = 0; ky < 3; ++ky) {
                        int ry = pr - ky;
                        if (ry >= 0 && ry < 4) {
                            #pragma unroll
                            for (int kx = 0; kx < 3; ++kx)
                                #pragma unroll
                                for (int rx = 0; rx < 4; ++rx)
                                    acc[ry][rx] += e[rx+kx] * wr[ky*3+kx];
                        }
                    }
                }
            } else {
                #pragma unroll
                for (int pr = 0; pr < 9; ++pr) {
                    const float* row = ip + (2*sy+pr)*P + 2*sx;
                    float4 a = *(const float4*)row;
                    float4 b = *(const float4*)(row+4);
                    float c8 = row[8];
                    float e[9] = {a.x,a.y,a.z,a.w,b.x,b.y,b.z,b.w,c8};
                    #pragma unroll
                    for (int ky = 0; ky < 3; ++ky) {
                        int t = pr - ky;
                        if (t >= 0 && t < 8 && (t & 1) == 0) {
                            int ry = t >> 1;
                            #pragma unroll
                            for (int kx = 0; kx < 3; ++kx)
                                #pragma unroll
                                for (int rx = 0; rx < 4; ++rx)
                                    acc[ry][rx] += e[2*rx+kx] * wr[ky*3+kx];
                        }
                    }
                }
            }
        }
        __syncthreads();
    }

    float* op = out + ((size_t)n*Co + co0 + co)*Ho*Wo + (size_t)(ty0+sy)*Wo + (tx0+sx);
    #pragma unroll
    for (int ry=0; ry<4; ++ry) {
        float4 v;
        if constexpr (RELU) {
            v.x = fmaxf(acc[ry][0], 0.f); v.y = fmaxf(acc[ry][1], 0.f);
            v.z = fmaxf(acc[ry][2], 0.f); v.w = fmaxf(acc[ry][3], 0.f);
        } else {
            v.x = acc[ry][0]; v.y = acc[ry][1]; v.z = acc[ry][2]; v.w = acc[ry][3];
        }
        *(float4*)(op + (size_t)ry*Wo) = v;
    }
}

// ---------------- sum K partial slabs + relu ----------------
__global__ void reduce_relu(const float* __restrict__ part, float* __restrict__ out,
                            int L, int KS) {
    int i = (blockIdx.x*blockDim.x + threadIdx.x) * 4;
    if (i >= L) return;
    float4 s = *(const float4*)&part[i];
    for (int k = 1; k < KS; ++k) {
        float4 p = *(const float4*)&part[(size_t)k*L + i];
        s.x += p.x; s.y += p.y; s.z += p.z; s.w += p.w;
    }
    s.x = fmaxf(s.x, 0.f); s.y = fmaxf(s.y, 0.f);
    s.z = fmaxf(s.z, 0.f); s.w = fmaxf(s.w, 0.f);
    *(float4*)&out[i] = s;
}

// =====================================================================
// 7x7 s2 p3 conv + BN (f32 math). TO = float (global) or ushort bf16 (local)
// =====================================================================
template<typename TO>
__global__ __launch_bounds__(256) void conv7_bn_tiled(
    const float* __restrict__ x, const float* __restrict__ w,
    const float* __restrict__ gamma, const float* __restrict__ beta,
    const float* __restrict__ mean, const float* __restrict__ var,
    TO* __restrict__ out, int N)
{
    constexpr int TH=16, TW=16, CO_T=8, NT=256, NSP=32;
    constexpr int IT = 37;
    constexpr int P  = 38;
    constexpr int IN_ELEMS = 3*IT*IT;
    constexpr int W_ELEMS  = CO_T*3*49;

    __shared__ __align__(16) float s_in[3*IT*P];
    __shared__ __align__(16) float s_w[CO_T*3*7*8];

    int bx = blockIdx.x;
    const int spn = 4, cog = 8;
    const int sxb = bx % spn; bx /= spn;
    const int syb = bx % spn; bx /= spn;
    const int cg  = bx % cog; const int n = bx / cog;
    const int tx0 = sxb*TW, ty0 = syb*TH, co0 = cg*CO_T;

    const int tid = threadIdx.x;
    const int sp  = tid % NSP;
    const int co  = tid / NSP;
    const int sy  = (sp / 4) * 2;
    const int sx  = (sp % 4) * 4;

    const int y_in0 = ty0*2 - 3, x_in0 = tx0*2 - 3;
    const float* x_n = x + (size_t)n*3*16384;

    for (int idx = tid; idx < IN_ELEMS; idx += NT) {
        int ci  = idx / (IT*IT);
        int rem = idx - ci*(IT*IT);
        int iy  = rem / IT;
        int ix  = rem - iy*IT;
        int gy = y_in0 + iy, gx = x_in0 + ix;
        float v = 0.f;
        if ((unsigned)gy < 128u && (unsigned)gx < 128u)
            v = x_n[(size_t)ci*16384 + gy*128 + gx];
        s_in[ci*(IT*P) + iy*P + ix] = v;
    }
    for (int idx = tid; idx < W_ELEMS; idx += NT) {
        int c   = idx / 147;
        int rem = idx - c*147;
        int ci  = rem / 49;
        int rem2= rem - ci*49;
        int ky  = rem2 / 7, kx = rem2 - ky*7;
        s_w[((c*3 + ci)*7 + ky)*8 + kx] = w[(size_t)(co0+c)*147 + ci*49 + ky*7 + kx];
    }
    __syncthreads();

    float acc[2][4] = {{0.f,0.f,0.f,0.f},{0.f,0.f,0.f,0.f}};
    const int c0 = 2*sx;
    #pragma unroll 1
    for (int ci = 0; ci < 3; ++ci) {
        const float* ip = &s_in[ci*(IT*P)];
        #pragma unroll
        for (int pr = 0; pr < 9; ++pr) {
            const float* row = ip + (2*sy+pr)*P + c0;
            float2 q0 = *(const float2*)(row+0);
            float2 q1 = *(const float2*)(row+2);
            float2 q2 = *(const float2*)(row+4);
            float2 q3 = *(const float2*)(row+6);
            float2 q4 = *(const float2*)(row+8);
            float2 q5 = *(const float2*)(row+10);
            float  e12 = row[12];
            float e[13] = {q0.x,q0.y,q1.x,q1.y,q2.x,q2.y,q3.x,q3.y,q4.x,q4.y,q5.x,q5.y,e12};
            #pragma unroll
            for (int ry = 0; ry < 2; ++ry) {
                int ky = pr - 2*ry;
                if (ky >= 0 && ky < 7) {
                    const float* wrow = &s_w[((co*3 + ci)*7 + ky)*8];
                    float4 wa = *(const float4*)wrow;
                    float2 wbv = *(const float2*)(wrow+4);
                    float w6 = wrow[6];
                    float wk[7] = {wa.x,wa.y,wa.z,wa.w,wbv.x,wbv.y,w6};
                    #pragma unroll
                    for (int kx = 0; kx < 7; ++kx)
                        #pragma unroll
                        for (int rx = 0; rx < 4; ++rx)
                            acc[ry][rx] += e[2*rx+kx] * wk[kx];
                }
            }
        }
    }

    const int coo = co0 + co;
    float inv = gamma[coo] / sqrtf(var[coo] + 1e-5f);
    float mu = mean[coo], bb = beta[coo];
    TO* op = out + ((size_t)n*64 + coo)*4096 + (size_t)(ty0+sy)*64 + (tx0+sx);
    #pragma unroll
    for (int ry=0; ry<2; ++ry) {
        float v0 = (acc[ry][0]-mu)*inv + bb; float v1 = (acc[ry][1]-mu)*inv + bb;
        float v2 = (acc[ry][2]-mu)*inv + bb; float v3 = (acc[ry][3]-mu)*inv + bb;
        if constexpr (sizeof(TO) == 4) {
            float4 v; v.x=v0; v.y=v1; v.z=v2; v.w=v3;
            *(float4*)((float*)op + (size_t)ry*64) = v;
        } else {
            ushort4 u; u.x=f2b(v0); u.y=f2b(v1); u.z=f2b(v2); u.w=f2b(v3);
            *(ushort4*)((ushort*)op + (size_t)ry*64) = u;
        }
    }
}

// ---------------- weight f32 -> bf16 cast ----------------
__global__ void wcast(const float* __restrict__ src, ushort* __restrict__ dst, int n) {
    int i = blockIdx.x*blockDim.x + threadIdx.x;
    if (i < n) dst[i] = f2b(src[i]);
}

// ---------------- im2row (bf16 NCHW -> Brow[p][k]) ----------------
__global__ void im2row_k(const ushort* __restrict__ in, ushort* __restrict__ Brow,
                         int n0, int NN, int Ci, int Hi, int Wi, int Ho, int Wo,
                         int stride, int K) {
    int idx = blockIdx.x*blockDim.x + threadIdx.x;
    int K8 = K >> 3;
    if (idx >= NN * K8) return;
    int ks = idx % K8;
    int p  = idx / K8;
    int xo = p % Wo; int t = p / Wo; int yo = t % Ho; int nl = t / Ho;
    const ushort* ip = in + (size_t)(n0 + nl)*Ci*Hi*Wi;
    int y0 = yo*stride - 1, x0 = xo*stride - 1;
    us8 v;
    #pragma unroll
    for (int j = 0; j < 8; ++j) {
        int k = ks*8 + j;
        int ci = k / 9, tt = k - ci*9;
        int ky = tt / 3, kx = tt - ky*3;
        int yi = y0 + ky, xi = x0 + kx;
        ushort val = 0;
        if ((unsigned)yi < (unsigned)Hi && (unsigned)xi < (unsigned)Wi)
            val = ip[(size_t)ci*Hi*Wi + yi*Wi + xi];
        v[j] = val;
    }
    *(us8*)&Brow[(size_t)p*K + ks*8] = v;
}

// ---------------- bf16 MFMA GEMM (verified round 6) ----------------
__global__ __launch_bounds__(256) void gemm_conv(
    const ushort* __restrict__ A, const ushort* __restrict__ B,
    ushort* __restrict__ out,
    int M, int K, int NN, int Co, int hwShift, int n0)
{
    __shared__ __align__(16) ushort sA[64*32];
    __shared__ __align__(16) ushort sB[128*32];

    int bx = blockIdx.x;
    int mtiles = M >> 6;
    int mt = bx % mtiles;
    int nt = bx / mtiles;
    int co0 = mt << 6, p0 = nt << 7;
    int tid = threadIdx.x, lane = tid & 63, wave = tid >> 6;
    int wm = wave & 1, wn = wave >> 1;

    f4v acc[2][4];
    #pragma unroll
    for (int i=0;i<2;++i)
        #pragma unroll
        for (int j=0;j<4;++j)
            #pragma unroll
            for (int r=0;r<4;++r) acc[i][j][r] = 0.f;

    const int g  = lane >> 4;
    const int li = lane & 15;

    for (int k0 = 0; k0 < K; k0 += 32) {
        {
            int r = tid >> 2, s = tid & 3;
            int sp = s ^ ((r >> 1) & 3);
            us8 val = *(const us8*)&A[(size_t)(co0 + r)*K + k0 + s*8];
            *(us8*)&sA[r*32 + sp*8] = val;
        }
        #pragma unroll
        for (int h = 0; h < 2; ++h) {
            int slot = tid + h*256;
            int r = slot >> 2, s = slot & 3;
            int sp = s ^ ((r >> 1) & 3);
            us8 val = *(const us8*)&B[(size_t)(p0 + r)*K + k0 + s*8];
            *(us8*)&sB[r*32 + sp*8] = val;
        }
        __syncthreads();

        s8v a0, a1, b0, b1, b2, b3;
        {
            int r = wm*32 + li;
            a0 = *(const s8v*)&sA[r*32 + ((g ^ ((r>>1)&3)))*8];
            int r2 = r + 16;
            a1 = *(const s8v*)&sA[r2*32 + ((g ^ ((r2>>1)&3)))*8];
        }
        {
            int r = wn*64 + li;
            b0 = *(const s8v*)&sB[r*32 + ((g ^ ((r>>1)&3)))*8];
            int r1 = r + 16;
            b1 = *(const s8v*)&sB[r1*32 + ((g ^ ((r1>>1)&3)))*8];
            int r2 = r + 32;
            b2 = *(const s8v*)&sB[r2*32 + ((g ^ ((r2>>1)&3)))*8];
            int r3 = r + 48;
            b3 = *(const s8v*)&sB[r3*32 + ((g ^ ((r3>>1)&3)))*8];
        }
        acc[0][0] = __builtin_amdgcn_mfma_f32_16x16x32_bf16(a0, b0, acc[0][0], 0, 0, 0);
        acc[0][1] = __builtin_amdgcn_mfma_f32_16x16x32_bf16(a0, b1, acc[0][1], 0, 0, 0);
        acc[0][2] = __builtin_amdgcn_mfma_f32_16x16x32_bf16(a0, b2, acc[0][2], 0, 0, 0);
        acc[0][3] = __builtin_amdgcn_mfma_f32_16x16x32_bf16(a0, b3, acc[0][3], 0, 0, 0);
        acc[1][0] = __builtin_amdgcn_mfma_f32_16x16x32_bf16(a1, b0, acc[1][0], 0, 0, 0);
        acc[1][1] = __builtin_amdgcn_mfma_f32_16x16x32_bf16(a1, b1, acc[1][1], 0, 0, 0);
        acc[1][2] = __builtin_amdgcn_mfma_f32_16x16x32_bf16(a1, b2, acc[1][2], 0, 0, 0);
        acc[1][3] = __builtin_amdgcn_mfma_f32_16x16x32_bf16(a1, b3, acc[1][3], 0, 0, 0);
        __syncthreads();
    }

    int hwMask = (1 << hwShift) - 1;
    #pragma unroll
    for (int i = 0; i < 2; ++i) {
        #pragma unroll
        for (int j = 0; j < 4; ++j) {
            #pragma unroll
            for (int r = 0; r < 4; ++r) {
                int co = co0 + wm*32 + i*16 + g*4 + r;
                int p  = p0 + wn*64 + j*16 + li;
                int nimg = p >> hwShift, sphw = p & hwMask;
                float v = fmaxf(acc[i][j][r], 0.f);
                out[(((size_t)(n0 + nimg)*Co + co) << hwShift) + sphw] = f2b(v);
            }
        }
    }
}

// ---------------- per-row (64-elem) mean via wave reduce ----------------
template<typename T>
__global__ void row_mean64(const T* __restrict__ in, float* __restrict__ out, int rows) {
    int w = (blockIdx.x*blockDim.x + threadIdx.x) >> 6;
    int lane = threadIdx.x & 63;
    if (w >= rows) return;
    float v = tof(in[(size_t)w*64 + lane]);
    #pragma unroll
    for (int off = 32; off > 0; off >>= 1) v += __shfl_down(v, off, 64);
    if (lane == 0) out[w] = v * (1.f/64.f);
}

// ---------------- classifier head ----------------
__global__ void head_sigmoid(const float* __restrict__ m, const float* __restrict__ cw,
                             const float* __restrict__ cb, float* __restrict__ out0,
                             float* __restrict__ out1, int Nrows) {
    int idx = blockIdx.x*blockDim.x + threadIdx.x;
    if (idx >= Nrows*20) return;
    int o = idx % 20, n = idx / 20;
    const float* mp = m + (size_t)n*1024;
    const float* wp = cw + (size_t)o*1024;
    float s = cb[o];
    for (int c=0;c<1024;++c) s += mp[c]*wp[c];
    float v = 1.f/(1.f+expf(-s));
    out0[idx] = v;
    if (out1) out1[idx] = v;
}

// ---------------- cam ----------------
__global__ void cam_kernel(const float* __restrict__ act, const float* __restrict__ cw,
                           const float* __restrict__ cb, float* __restrict__ cam, int N) {
    int idx = blockIdx.x*blockDim.x + threadIdx.x;
    if (idx >= N*20*64) return;
    int p = idx & 63; int o = (idx>>6) % 20; int n = idx / 1280;
    const float* a = act + (size_t)n*1024*64 + p;
    const float* wp = cw + (size_t)o*1024;
    float s = cb[o];
    for (int c=0;c<1024;++c) s += a[c*64]*wp[c];
    cam[idx] = 1.f/(1.f+expf(-s));
}

// ---------------- bilinear resize cam ----------------
__global__ void resize_cam(const float* __restrict__ cam, float* __restrict__ cs, int N) {
    int idx = blockIdx.x*blockDim.x + threadIdx.x;
    if (idx >= N*20*16384) return;
    int xo = idx & 127, yo = (idx>>7)&127;
    int bo = idx >> 14;
    float fy = (float)yo * (7.0f/127.0f);
    float fx = (float)xo * (7.0f/127.0f);
    int y0 = (int)floorf(fy); float wy = fy - (float)y0;
    int x0 = (int)floorf(fx); float wx = fx - (float)x0;
    if (y0 > 7) y0 = 7; if (y0 < 0) y0 = 0; int y1 = min(y0+1, 7);
    if (x0 > 7) x0 = 7; if (x0 < 0) x0 = 0; int x1 = min(x0+1, 7);
    const float* c = cam + (size_t)bo*64;
    float v = (1.f-wy)*((1.f-wx)*c[y0*8+x0] + wx*c[y0*8+x1])
            +      wy *((1.f-wx)*c[y1*8+x0] + wx*c[y1*8+x1]);
    cs[idx] = v;
}

// ---------------- wscore / hscore max reductions ----------------
__global__ void score_maxred(const float* __restrict__ cs, float* __restrict__ wsc,
                             float* __restrict__ hsc, int N) {
    int idx = blockIdx.x*blockDim.x + threadIdx.x;
    int total = N*20*128;
    if (idx >= 2*total) return;
    if (idx < total) {
        int wcol = idx % 128; int bo = idx / 128;
        const float* p = cs + (size_t)bo*16384 + wcol;
        float mv = -1e30f;
        for (int h=0; h<128; ++h) mv = fmaxf(mv, p[h*128]);
        wsc[idx] = mv;
    } else {
        int i = idx - total;
        int hrow = i % 128; int bo = i / 128;
        const float* p = cs + (size_t)bo*16384 + hrow*128;
        float mv = -1e30f;
        for (int w_=0; w_<128; ++w_) mv = fmaxf(mv, p[w_]);
        hsc[i] = mv;
    }
}

// ---------------- stable top-4 of 20 per batch ----------------
__global__ void topk4(const float* __restrict__ gs, int* __restrict__ top, int N) {
    int n = threadIdx.x;
    if (n >= N) return;
    const float* g = gs + n*20;
    bool used[20];
    for (int i=0;i<20;++i) used[i]=false;
    for (int t=0;t<4;++t) {
        int bi = -1; float bv = -1e30f;
        for (int i=0;i<20;++i) {
            if (!used[i] && g[i] > bv) { bv = g[i]; bi = i; }
        }
        used[bi] = true;
        top[n*4+t] = bi;
    }
}

// ---------------- gather top rows + norm01 ----------------
__global__ void gather_norm(const float* __restrict__ wsc, const float* __restrict__ hsc,
                            const int* __restrict__ top, float* __restrict__ xs,
                            float* __restrict__ ysn, int N) {
    int r = blockIdx.x;
    int axis = r / (N*4); int row = r % (N*4);
    int b = row / 4;
    int cls = top[row];
    const float* src = (axis==0 ? wsc : hsc) + ((size_t)b*20 + cls)*128;
    int t = threadIdx.x;
    float v = src[t];
    __shared__ float smn[128], smx[128];
    smn[t] = v; smx[t] = v;
    __syncthreads();
    for (int off=64; off>0; off>>=1) {
        if (t < off) { smn[t] = fminf(smn[t], smn[t+off]); smx[t] = fmaxf(smx[t], smx[t+off]); }
        __syncthreads();
    }
    float mn = smn[0], mx = smx[0];
    float outv;
    if (mx == mn) outv = v / (mx == 0.f ? 1.f : mx);
    else          outv = (v - mn) / (mx - mn);
    (axis==0 ? xs : ysn)[row*128 + t] = outv;
}

// ---------------- obj_loc ----------------
__global__ void objloc(const float* __restrict__ xs, const float* __restrict__ ysn,
                       int* __restrict__ box, int N) {
    int i = threadIdx.x;
    if (i >= 2*N*4) return;
    int axis = i / (N*4); int row = i % (N*4);
    const float* s = (axis ? ysn : xs) + (size_t)row*128;
    const int S = 128, minsize = 16;
    int pos[127]; int ncross = 0;
    int prev = sgnf(s[0] - 0.5f);
    for (int k=1; k<S; ++k) {
        int cur = sgnf(s[k] - 0.5f);
        int d = cur - prev; if (d < 0) d = -d;
        if (d == 2) pos[ncross++] = k-1;
        prev = cur;
    }
    float m = -1e30f;
    for (int k=0; k<S; ++k) m = fmaxf(m, s[k]);
    int zmin = 0, zmax = S, bestkey = -2;
    int a = 0;
    for (int j=0; j<=ncross; ++j) {
        int bnd = (j < ncross) ? pos[j] : S;
        float sm = -1e30f;
        for (int k=a; k<bnd; ++k) sm = fmaxf(sm, s[k]);
        int len = bnd - a;
        int key = (sm == m) ? len : -1;
        if (key > bestkey) { bestkey = key; zmin = a; zmax = bnd; }
        a = bnd;
    }
    bool need = (zmax - zmin) <= minsize;
    int pad = minsize - (zmax - zmin);
    int cp = (pad + 1) >> 1;
    bool c1 = need && (zmin > cp) && (S - zmax > pad);
    if (c1) { zmin = zmin - cp + 1; zmax = zmax + cp; }
    bool c2 = need && (zmin < cp);
    if (c2) { zmin = 0; zmax = minsize; }
    bool c3 = need && (S - zmax < cp);
    if (c3) { zmin = S - minsize + 1; zmax = S; }
    if (ncross == 0) { zmin = minsize; zmax = 112; }
    if (axis == 0) { box[row] = zmin; box[32+row] = zmax; }
    else           { box[64+row] = zmin; box[96+row] = zmax; }
}

// ---------------- crop + bilinear resize ----------------
__global__ void crop_resize_k(const float* __restrict__ x, const int* __restrict__ box,
                              float* __restrict__ lin, int N) {
    int idx = blockIdx.x*blockDim.x + threadIdx.x;
    if (idx >= N*4*3*16384) return;
    int xo = idx & 127, yo = (idx>>7)&127;
    int c  = (idx>>14) % 3;
    int r  = idx / 49152;
    int b  = r / 4;
    int cx1 = box[r],    cx2 = box[32+r];
    int cy1 = box[64+r], cy2 = box[96+r];
    float fy = (float)cy1 + (float)(yo * (cy2 - 1 - cy1)) / 127.0f;
    float fx = (float)cx1 + (float)(xo * (cx2 - 1 - cx1)) / 127.0f;
    float wy = fy - floorf(fy);
    float wx = fx - floorf(fx);
    int y0 = min(max((int)floorf(fy), 0), 127); int y1 = min(y0 + 1, 127);
    int x0 = min(max((int)floorf(fx), 0), 127); int x1 = min(x0 + 1, 127);
    const float* img = x + ((size_t)b*3 + c)*16384;
    float v = (1.f-wy)*((1.f-wx)*img[y0*128+x0] + wx*img[y0*128+x1])
            +      wy *((1.f-wx)*img[y1*128+x0] + wx*img[y1*128+x1]);
    lin[idx] = v;
}

// ---------------- local_stream = max over TOPN ----------------
__global__ void local_stream_max(const float* __restrict__ loc, float* __restrict__ out, int N) {
    int idx = threadIdx.x;
    if (idx >= N*20) return;
    int o = idx % 20, b = idx / 20;
    float mv = -1e30f;
    for (int t=0; t<4; ++t) mv = fmaxf(mv, loc[((size_t)(b*4+t))*20 + o]);
    out[idx] = mv;
}

// ---------------- f32 conv stack (4x4 reg tile, K-split w3/w4) ----------------
static void run_stack_f32(const float* input, int n,
                          const float* c1w, const float* bng, const float* bnb,
                          const float* bnm, const float* bnv,
                          const float* w1, const float* w2, const float* w3, const float* w4,
                          float* bufA, float* bufB, float* act, hipStream_t stream) {
    float* w3out = bufB + (size_t)n*512*256*2;
    conv7_bn_tiled<float><<<4*4*8*n, 256, 0, stream>>>(input, c1w, bng, bnb, bnm, bnv, bufA, n);
    // w1 3x3 s1: 64->128 @64x64
    conv3_t44<1,16,16,16,8,256,20,true><<<4*4*8*n, 256, 0, stream>>>(bufA, w1, bufB, n, 64, 128, 64,64, 64,64, 0);
    // w2 3x3 s2: 128->256, 64->32
    conv3_t44<2,8,16,32,8,256,36,true><<<2*4*8*n, 256, 0, stream>>>(bufB, w2, bufA, n, 128, 256, 64,64, 32,32, 0);
    // w3 3x3 s2: 256->512, 32->16 — KS=2
    {
        dim3 grid(1*2*16*n, 2);
        conv3_t44<2,8,16,32,8,256,36,false><<<grid, 256, 0, stream>>>(bufA, w3, bufB, n, 256, 512, 32,32, 16,16, 128);
        int L = n*512*256;
        reduce_relu<<<(L/4+255)/256, 256, 0, stream>>>(bufB, w3out, L, 2);
    }
    // w4 3x3 s2: 512->1024, 16->8 — KS=4
    {
        dim3 grid(1*1*16*n, 4);
        conv3_t44<2,8,8,64,8,256,20,false><<<grid, 256, 0, stream>>>(w3out, w4, bufA, n, 512, 1024, 16,16, 8,8, 128);
        int L = n*1024*64;
        reduce_relu<<<(L/4+255)/256, 256, 0, stream>>>(bufA, act, L, 4);
    }
}

// ---------------- launcher ----------------
extern "C" void kernel_launch(void* const* d_in, const int* in_sizes, int n_in,
                              void* d_out_, int out_size, void* d_ws, size_t ws_size,
                              hipStream_t stream) {
    const float* x    = (const float*)d_in[0];
    const float* c1w  = (const float*)d_in[1];
    const float* bng  = (const float*)d_in[2];
    const float* bnb  = (const float*)d_in[3];
    const float* bnm  = (const float*)d_in[4];
    const float* bnv  = (const float*)d_in[5];
    const float* w1   = (const float*)d_in[6];
    const float* w2   = (const float*)d_in[7];
    const float* w3   = (const float*)d_in[8];
    const float* w4   = (const float*)d_in[9];
    const float* clsw = (const float*)d_in[10];
    const float* clsb = (const float*)d_in[11];
    float* dout = (float*)d_out_;

    float* out_gs = dout + 0;
    float* out_ls = dout + 160;
    float* out_cs = dout + 320;
    float* out_ws = dout + 2621760;
    float* out_hs = dout + 2642240;
    float* out_li = dout + 2662720;

    const size_t NEED = 101662720ull;
    if (ws_size >= NEED) {
        char* wsb = (char*)d_ws;
        ushort* wb1 = (ushort*)(wsb + 0);
        ushort* wb2 = (ushort*)(wsb + 147456);
        ushort* wb3 = (ushort*)(wsb + 737280);
        ushort* wb4 = (ushort*)(wsb + 3096576);
        ushort* R1  = (ushort*)(wsb + 12533760);
        ushort* R2  = (ushort*)(wsb + 29310976);
        ushort* BR  = (ushort*)(wsb + 62865408);
        float* gA   = (float*)(wsb + 62865408);
        float* gB   = (float*)(wsb + 62865408 + 8388608);
        float* gact = (float*)(wsb + 62865408 + 25165824);
        char* smb = wsb + 100614144;
        float* gmean = (float*)(smb);
        float* gst   = (float*)(smb + 32768);
        float* cam   = (float*)(smb + 33408);
        int*   top   = (int*)  (smb + 74368);
        float* xs    = (float*)(smb + 74496);
        float* ysn   = (float*)(smb + 90880);
        int*   box   = (int*)  (smb + 107264);
        float* lmean = (float*)(smb + 107776);
        float* locf  = (float*)(smb + 238848);

        wcast<<<288,256,0,stream>>>(w1, wb1, 73728);
        wcast<<<1152,256,0,stream>>>(w2, wb2, 294912);
        wcast<<<4608,256,0,stream>>>(w3, wb3, 1179648);
        wcast<<<18432,256,0,stream>>>(w4, wb4, 4718592);

        // ---- global branch (f32, feeds discrete decisions) ----
        run_stack_f32(x, 8, c1w, bng, bnb, bnm, bnv, w1, w2, w3, w4, gA, gB, gact, stream);
        row_mean64<float><<<2048,256,0,stream>>>(gact, gmean, 8192);
        head_sigmoid<<<1,256,0,stream>>>(gmean, clsw, clsb, gst, out_gs, 8);
        cam_kernel<<<40,256,0,stream>>>(gact, clsw, clsb, cam, 8);
        resize_cam<<<10240,256,0,stream>>>(cam, out_cs, 8);
        score_maxred<<<160,256,0,stream>>>(out_cs, out_ws, out_hs, 8);
        topk4<<<1,64,0,stream>>>(gst, top, 8);
        gather_norm<<<64,128,0,stream>>>(out_ws, out_hs, top, xs, ysn, 8);
        objloc<<<1,64,0,stream>>>(xs, ysn, box, 8);
        crop_resize_k<<<6144,256,0,stream>>>(x, box, out_li, 8);

        // ---- local branch (bf16 MFMA) ----
        conv7_bn_tiled<ushort><<<4*4*8*32, 256, 0, stream>>>(out_li, c1w, bng, bnb, bnm, bnv, R1, 32);
        for (int c = 0; c < 4; ++c) {
            im2row_k<<<9216,256,0,stream>>>(R1, BR, c*8, 32768, 64, 64, 64, 64, 64, 1, 576);
            gemm_conv<<<512,256,0,stream>>>(wb1, BR, R2, 128, 576, 32768, 128, 12, c*8);
        }
        for (int c = 0; c < 2; ++c) {
            im2row_k<<<9216,256,0,stream>>>(R2, BR, c*16, 16384, 128, 64, 64, 32, 32, 2, 1152);
            gemm_conv<<<512,256,0,stream>>>(wb2, BR, R1, 256, 1152, 16384, 256, 10, c*16);
        }
        im2row_k<<<9216,256,0,stream>>>(R1, BR, 0, 8192, 256, 32, 32, 16, 16, 2, 2304);
        gemm_conv<<<512,256,0,stream>>>(wb3, BR, R2, 512, 2304, 8192, 512, 8, 0);
        im2row_k<<<4608,256,0,stream>>>(R2, BR, 0, 2048, 512, 16, 16, 8, 8, 2, 4608);
        gemm_conv<<<256,256,0,stream>>>(wb4, BR, R1, 1024, 4608, 2048, 1024, 6, 0);

        row_mean64<ushort><<<8192,256,0,stream>>>(R1, lmean, 32768);
        head_sigmoid<<<3,256,0,stream>>>(lmean, clsw, clsb, locf, (float*)nullptr, 32);
        local_stream_max<<<1,256,0,stream>>>(locf, out_ls, 8);
    } else {
        // -------- f32 fallback --------
        float* ws = (float*)d_ws;
        float* bufA  = ws + 0;
        float* bufB  = ws + 2097152;
        float* act   = ws + 6291456;
        float* gmean = ws + 6815744;
        float* gst   = ws + 6823936;
        float* cam   = ws + 6824096;
        int*   top   = (int*)(ws + 6834336);
        float* xs    = ws + 6834368;
        float* ysn   = ws + 6838464;
        int*   box   = (int*)(ws + 6842560);
        float* lmean = ws + 6842688;
        float* locf  = ws + 6875456;

        run_stack_f32(x, 8, c1w, bng, bnb, bnm, bnv, w1, w2, w3, w4, bufA, bufB, act, stream);
        row_mean64<float><<<2048,256,0,stream>>>(act, gmean, 8192);
        head_sigmoid<<<1,256,0,stream>>>(gmean, clsw, clsb, gst, out_gs, 8);
        cam_kernel<<<40,256,0,stream>>>(act, clsw, clsb, cam, 8);
        resize_cam<<<10240,256,0,stream>>>(cam, out_cs, 8);
        score_maxred<<<160,256,0,stream>>>(out_cs, out_ws, out_hs, 8);
        topk4<<<1,64,0,stream>>>(gst, top, 8);
        gather_norm<<<64,128,0,stream>>>(out_ws, out_hs, top, xs, ysn, 8);
        objloc<<<1,64,0,stream>>>(xs, ysn, box, 8);
        crop_resize_k<<<6144,256,0,stream>>>(x, box, out_li, 8);

        for (int c = 0; c < 4; ++c) {
            const float* lin_c = out_li + (size_t)c*8*3*16384;
            run_stack_f32(lin_c, 8, c1w, bng, bnb, bnm, bnv, w1, w2, w3, w4, bufA, bufB, act, stream);
            row_mean64<float><<<2048,256,0,stream>>>(act, lmean + c*8192, 8192);
        }
        head_sigmoid<<<3,256,0,stream>>>(lmean, clsw, clsb, locf, (float*)nullptr, 32);
        local_stream_max<<<1,256,0,stream>>>(locf, out_ls, 8);
    }
}

// Round 9
// 1489.002 us; speedup vs baseline: 1.1117x; 1.1117x over previous
//
#include <hip/hip_runtime.h>
#include <hip/hip_bf16.h>

// ---------------- helpers ----------------
__device__ __forceinline__ int sgnf(float v){ return (v>0.f)-(v<0.f); }
__device__ __forceinline__ ushort f2b(float f){ __hip_bfloat16 h = __float2bfloat16(f); return __builtin_bit_cast(ushort, h); }
__device__ __forceinline__ float  b2f(ushort u){ __hip_bfloat16 h = __builtin_bit_cast(__hip_bfloat16, u); return __bfloat162float(h); }
__device__ __forceinline__ float  tof(float v){ return v; }
__device__ __forceinline__ float  tof(ushort v){ return b2f(v); }

typedef short  s8v  __attribute__((ext_vector_type(8)));
typedef ushort us8  __attribute__((ext_vector_type(8)));
typedef float  f4v  __attribute__((ext_vector_type(4)));

// =====================================================================
// f32 tiled 3x3 conv (round-7 verified 2x4 tile).
// RELU=true: full conv + relu. RELU=false: K-split partial (raw, slab y).
// =====================================================================
template<int STRIDE, int TH, int TW, int CO_T, int CI_T, int NT, int P, bool RELU>
__global__ __launch_bounds__(NT) void conv3_tiled(
    const float* __restrict__ in, const float* __restrict__ w, float* __restrict__ out,
    int N, int Ci, int Co, int Hi, int Wi, int Ho, int Wo, int ciLen)
{
    constexpr int NSP   = (TH/2)*(TW/4);
    constexpr int IT_H  = (TH-1)*STRIDE + 3;
    constexpr int IT_W  = (TW-1)*STRIDE + 3;
    constexpr int IN_ELEMS = CI_T*IT_H*IT_W;
    constexpr int W_ELEMS  = CI_T*CO_T*9;
    static_assert(NSP*CO_T == NT, "thread count mismatch");
    static_assert(IT_W <= P, "pitch too small");

    __shared__ __align__(16) float s_in[CI_T*IT_H*P];
    __shared__ __align__(16) float s_w[CI_T*CO_T*12];

    int bx = blockIdx.x;
    const int spxn = Wo/TW, spyn = Ho/TH, cog = Co/CO_T;
    const int sxb = bx % spxn; bx /= spxn;
    const int syb = bx % spyn; bx /= spyn;
    const int cg  = bx % cog;  const int n = bx / cog;
    const int tx0 = sxb*TW, ty0 = syb*TH, co0 = cg*CO_T;

    const int ciStart = RELU ? 0 : blockIdx.y * ciLen;
    const int ciEnd   = RELU ? Ci : ciStart + ciLen;
    if (!RELU) out += (size_t)blockIdx.y * N * Co * Ho * Wo;

    const int tid = threadIdx.x;
    const int sp  = tid % NSP;
    const int co  = tid / NSP;
    const int sy  = (sp / (TW/4)) * 2;
    const int sx  = (sp % (TW/4)) * 4;

    const int y_in0 = ty0*STRIDE - 1, x_in0 = tx0*STRIDE - 1;
    const float* in_n = in + (size_t)n*Ci*Hi*Wi;

    float acc[2][4] = {{0.f,0.f,0.f,0.f},{0.f,0.f,0.f,0.f}};

    for (int ci0 = ciStart; ci0 < ciEnd; ci0 += CI_T) {
        for (int idx = tid; idx < IN_ELEMS; idx += NT) {
            int ci  = idx / (IT_H*IT_W);
            int rem = idx - ci*(IT_H*IT_W);
            int iy  = rem / IT_W;
            int ix  = rem - iy*IT_W;
            int gy = y_in0 + iy, gx = x_in0 + ix;
            float v = 0.f;
            if ((unsigned)gy < (unsigned)Hi && (unsigned)gx < (unsigned)Wi)
                v = in_n[(size_t)(ci0+ci)*Hi*Wi + gy*Wi + gx];
            s_in[ci*(IT_H*P) + iy*P + ix] = v;
        }
        for (int idx = tid; idx < W_ELEMS; idx += NT) {
            int ci  = idx / (CO_T*9);
            int rem = idx - ci*(CO_T*9);
            int c   = rem / 9, k = rem - c*9;
            s_w[(ci*CO_T + c)*12 + k] = w[((size_t)(co0+c)*Ci + (ci0+ci))*9 + k];
        }
        __syncthreads();

        #pragma unroll
        for (int ci = 0; ci < CI_T; ++ci) {
            const float* wp = &s_w[(ci*CO_T + co)*12];
            float4 wa = *(const float4*)wp;
            float4 wb = *(const float4*)(wp+4);
            float w8  = wp[8];
            float wr[9] = {wa.x,wa.y,wa.z,wa.w, wb.x,wb.y,wb.z,wb.w, w8};
            const float* ip = &s_in[ci*(IT_H*P)];

            if constexpr (STRIDE == 1) {
                #pragma unroll
                for (int pr = 0; pr < 4; ++pr) {
                    const float* row = ip + (sy+pr)*P + sx;
                    float4 a = *(const float4*)row;
                    float2 b = *(const float2*)(row+4);
                    float e[6] = {a.x,a.y,a.z,a.w,b.x,b.y};
                    #pragma unroll
                    for (int ky = 0; ky < 3; ++ky) {
                        int ry = pr - ky;
                        if (ry == 0 || ry == 1) {
                            #pragma unroll
                            for (int kx = 0; kx < 3; ++kx)
                                #pragma unroll
                                for (int rx = 0; rx < 4; ++rx)
                                    acc[ry][rx] += e[rx+kx] * wr[ky*3+kx];
                        }
                    }
                }
            } else {
                #pragma unroll
                for (int pr = 0; pr < 5; ++pr) {
                    const float* row = ip + (2*sy+pr)*P + 2*sx;
                    float4 a = *(const float4*)row;
                    float4 b = *(const float4*)(row+4);
                    float c8 = row[8];
                    float e[9] = {a.x,a.y,a.z,a.w,b.x,b.y,b.z,b.w,c8};
                    #pragma unroll
                    for (int ky = 0; ky < 3; ++ky) {
                        int ry2 = pr - ky;
                        if (ry2 == 0 || ry2 == 2) {
                            int ry = ry2 >> 1;
                            #pragma unroll
                            for (int kx = 0; kx < 3; ++kx)
                                #pragma unroll
                                for (int rx = 0; rx < 4; ++rx)
                                    acc[ry][rx] += e[2*rx+kx] * wr[ky*3+kx];
                        }
                    }
                }
            }
        }
        __syncthreads();
    }

    float* op = out + ((size_t)n*Co + co0 + co)*Ho*Wo + (size_t)(ty0+sy)*Wo + (tx0+sx);
    #pragma unroll
    for (int ry=0; ry<2; ++ry) {
        float4 v;
        if constexpr (RELU) {
            v.x = fmaxf(acc[ry][0], 0.f); v.y = fmaxf(acc[ry][1], 0.f);
            v.z = fmaxf(acc[ry][2], 0.f); v.w = fmaxf(acc[ry][3], 0.f);
        } else {
            v.x = acc[ry][0]; v.y = acc[ry][1]; v.z = acc[ry][2]; v.w = acc[ry][3];
        }
        *(float4*)(op + (size_t)ry*Wo) = v;
    }
}

// ---------------- sum K partial slabs + relu ----------------
__global__ void reduce_relu(const float* __restrict__ part, float* __restrict__ out,
                            int L, int KS) {
    int i = (blockIdx.x*blockDim.x + threadIdx.x) * 4;
    if (i >= L) return;
    float4 s = *(const float4*)&part[i];
    for (int k = 1; k < KS; ++k) {
        float4 p = *(const float4*)&part[(size_t)k*L + i];
        s.x += p.x; s.y += p.y; s.z += p.z; s.w += p.w;
    }
    s.x = fmaxf(s.x, 0.f); s.y = fmaxf(s.y, 0.f);
    s.z = fmaxf(s.z, 0.f); s.w = fmaxf(s.w, 0.f);
    *(float4*)&out[i] = s;
}

// =====================================================================
// 7x7 s2 p3 conv + BN, f32 (global branch only now)
// =====================================================================
__global__ __launch_bounds__(256) void conv7_bn_tiled(
    const float* __restrict__ x, const float* __restrict__ w,
    const float* __restrict__ gamma, const float* __restrict__ beta,
    const float* __restrict__ mean, const float* __restrict__ var,
    float* __restrict__ out, int N)
{
    constexpr int IT = 37;
    constexpr int P  = 38;
    constexpr int NT = 256;
    constexpr int IN_ELEMS = 3*IT*IT;
    constexpr int W_ELEMS  = 8*3*49;

    __shared__ __align__(16) float s_in[3*IT*P];
    __shared__ __align__(16) float s_w[8*3*7*8];

    int bx = blockIdx.x;
    const int sxb = bx % 4; bx /= 4;
    const int syb = bx % 4; bx /= 4;
    const int cg  = bx % 8; const int n = bx / 8;
    const int tx0 = sxb*16, ty0 = syb*16, co0 = cg*8;

    const int tid = threadIdx.x;
    const int sp  = tid % 32;
    const int co  = tid / 32;
    const int sy  = (sp / 4) * 2;
    const int sx  = (sp % 4) * 4;

    const int y_in0 = ty0*2 - 3, x_in0 = tx0*2 - 3;
    const float* x_n = x + (size_t)n*3*16384;

    for (int idx = tid; idx < IN_ELEMS; idx += NT) {
        int ci  = idx / (IT*IT);
        int rem = idx - ci*(IT*IT);
        int iy  = rem / IT;
        int ix  = rem - iy*IT;
        int gy = y_in0 + iy, gx = x_in0 + ix;
        float v = 0.f;
        if ((unsigned)gy < 128u && (unsigned)gx < 128u)
            v = x_n[(size_t)ci*16384 + gy*128 + gx];
        s_in[ci*(IT*P) + iy*P + ix] = v;
    }
    for (int idx = tid; idx < W_ELEMS; idx += NT) {
        int c   = idx / 147;
        int rem = idx - c*147;
        int ci  = rem / 49;
        int rem2= rem - ci*49;
        int ky  = rem2 / 7, kx = rem2 - ky*7;
        s_w[((c*3 + ci)*7 + ky)*8 + kx] = w[(size_t)(co0+c)*147 + ci*49 + ky*7 + kx];
    }
    __syncthreads();

    float acc[2][4] = {{0.f,0.f,0.f,0.f},{0.f,0.f,0.f,0.f}};
    const int c0 = 2*sx;
    #pragma unroll 1
    for (int ci = 0; ci < 3; ++ci) {
        const float* ip = &s_in[ci*(IT*P)];
        #pragma unroll
        for (int pr = 0; pr < 9; ++pr) {
            const float* row = ip + (2*sy+pr)*P + c0;
            float2 q0 = *(const float2*)(row+0);
            float2 q1 = *(const float2*)(row+2);
            float2 q2 = *(const float2*)(row+4);
            float2 q3 = *(const float2*)(row+6);
            float2 q4 = *(const float2*)(row+8);
            float2 q5 = *(const float2*)(row+10);
            float  e12 = row[12];
            float e[13] = {q0.x,q0.y,q1.x,q1.y,q2.x,q2.y,q3.x,q3.y,q4.x,q4.y,q5.x,q5.y,e12};
            #pragma unroll
            for (int ry = 0; ry < 2; ++ry) {
                int ky = pr - 2*ry;
                if (ky >= 0 && ky < 7) {
                    const float* wrow = &s_w[((co*3 + ci)*7 + ky)*8];
                    float4 wa = *(const float4*)wrow;
                    float2 wbv = *(const float2*)(wrow+4);
                    float w6 = wrow[6];
                    float wk[7] = {wa.x,wa.y,wa.z,wa.w,wbv.x,wbv.y,w6};
                    #pragma unroll
                    for (int kx = 0; kx < 7; ++kx)
                        #pragma unroll
                        for (int rx = 0; rx < 4; ++rx)
                            acc[ry][rx] += e[2*rx+kx] * wk[kx];
                }
            }
        }
    }

    const int coo = co0 + co;
    float inv = gamma[coo] / sqrtf(var[coo] + 1e-5f);
    float mu = mean[coo], bb = beta[coo];
    float* op = out + ((size_t)n*64 + coo)*4096 + (size_t)(ty0+sy)*64 + (tx0+sx);
    #pragma unroll
    for (int ry=0; ry<2; ++ry) {
        float4 v;
        v.x = (acc[ry][0]-mu)*inv + bb; v.y = (acc[ry][1]-mu)*inv + bb;
        v.z = (acc[ry][2]-mu)*inv + bb; v.w = (acc[ry][3]-mu)*inv + bb;
        *(float4*)(op + (size_t)ry*64) = v;
    }
}

// ---------------- weight casts ----------------
__global__ void wcast(const float* __restrict__ src, ushort* __restrict__ dst, int n) {
    int i = blockIdx.x*blockDim.x + threadIdx.x;
    if (i < n) dst[i] = f2b(src[i]);
}
// conv1 weights -> A[64][160] (147 real + pad)
__global__ void wcast7(const float* __restrict__ src, ushort* __restrict__ dst) {
    int i = blockIdx.x*blockDim.x + threadIdx.x;
    if (i >= 64*160) return;
    int co = i / 160, k = i - co*160;
    dst[i] = (k < 147) ? f2b(src[co*147 + k]) : (ushort)0;
}
// BN affine prep: s = gamma/sqrt(var+eps), b = beta - mean*s
__global__ void bnprep(const float* __restrict__ g, const float* __restrict__ be,
                       const float* __restrict__ mu, const float* __restrict__ va,
                       float* __restrict__ s, float* __restrict__ b) {
    int i = threadIdx.x;
    if (i >= 64) return;
    float sv = g[i] / sqrtf(va[i] + 1e-5f);
    s[i] = sv;
    b[i] = be[i] - mu[i]*sv;
}

// ---------------- im2row (bf16 NCHW -> Brow[p][k]) for 3x3 ----------------
__global__ void im2row_k(const ushort* __restrict__ in, ushort* __restrict__ Brow,
                         int n0, int NN, int Ci, int Hi, int Wi, int Ho, int Wo,
                         int stride, int K) {
    int idx = blockIdx.x*blockDim.x + threadIdx.x;
    int K8 = K >> 3;
    if (idx >= NN * K8) return;
    int ks = idx % K8;
    int p  = idx / K8;
    int xo = p % Wo; int t = p / Wo; int yo = t % Ho; int nl = t / Ho;
    const ushort* ip = in + (size_t)(n0 + nl)*Ci*Hi*Wi;
    int y0 = yo*stride - 1, x0 = xo*stride - 1;
    us8 v;
    #pragma unroll
    for (int j = 0; j < 8; ++j) {
        int k = ks*8 + j;
        int ci = k / 9, tt = k - ci*9;
        int ky = tt / 3, kx = tt - ky*3;
        int yi = y0 + ky, xi = x0 + kx;
        ushort val = 0;
        if ((unsigned)yi < (unsigned)Hi && (unsigned)xi < (unsigned)Wi)
            val = ip[(size_t)ci*Hi*Wi + yi*Wi + xi];
        v[j] = val;
    }
    *(us8*)&Brow[(size_t)p*K + ks*8] = v;
}

// ---------------- im2row for conv1 7x7 s2 p3: f32 input -> bf16 rows K=160 ----------------
__global__ void im2row7(const float* __restrict__ in, ushort* __restrict__ Brow,
                        int n0, int NN) {
    int idx = blockIdx.x*blockDim.x + threadIdx.x;
    if (idx >= NN * 20) return;   // K8 = 160/8 = 20
    int ks = idx % 20;
    int p  = idx / 20;
    int xo = p & 63; int t = p >> 6; int yo = t & 63; int nl = t >> 6;
    const float* ip = in + (size_t)(n0 + nl)*3*16384;
    int y0 = yo*2 - 3, x0 = xo*2 - 3;
    us8 v;
    #pragma unroll
    for (int j = 0; j < 8; ++j) {
        int k = ks*8 + j;
        ushort val = 0;
        if (k < 147) {
            int ci = k / 49, tt = k - ci*49;
            int ky = tt / 7, kx = tt - ky*7;
            int yi = y0 + ky, xi = x0 + kx;
            if ((unsigned)yi < 128u && (unsigned)xi < 128u)
                val = f2b(ip[(size_t)ci*16384 + yi*128 + xi]);
        }
        v[j] = val;
    }
    *(us8*)&Brow[(size_t)p*160 + ks*8] = v;
}

// ---------------- bf16 MFMA GEMM; epilogue relu (sc==null) or BN affine ----------------
__global__ __launch_bounds__(256) void gemm_conv(
    const ushort* __restrict__ A, const ushort* __restrict__ B,
    ushort* __restrict__ out,
    int M, int K, int NN, int Co, int hwShift, int n0,
    const float* __restrict__ sc, const float* __restrict__ bi)
{
    __shared__ __align__(16) ushort sA[64*32];
    __shared__ __align__(16) ushort sB[128*32];

    int bx = blockIdx.x;
    int mtiles = M >> 6;
    int mt = bx % mtiles;
    int nt = bx / mtiles;
    int co0 = mt << 6, p0 = nt << 7;
    int tid = threadIdx.x, lane = tid & 63, wave = tid >> 6;
    int wm = wave & 1, wn = wave >> 1;

    f4v acc[2][4];
    #pragma unroll
    for (int i=0;i<2;++i)
        #pragma unroll
        for (int j=0;j<4;++j)
            #pragma unroll
            for (int r=0;r<4;++r) acc[i][j][r] = 0.f;

    const int g  = lane >> 4;
    const int li = lane & 15;

    for (int k0 = 0; k0 < K; k0 += 32) {
        {
            int r = tid >> 2, s = tid & 3;
            int sp = s ^ ((r >> 1) & 3);
            us8 val = *(const us8*)&A[(size_t)(co0 + r)*K + k0 + s*8];
            *(us8*)&sA[r*32 + sp*8] = val;
        }
        #pragma unroll
        for (int h = 0; h < 2; ++h) {
            int slot = tid + h*256;
            int r = slot >> 2, s = slot & 3;
            int sp = s ^ ((r >> 1) & 3);
            us8 val = *(const us8*)&B[(size_t)(p0 + r)*K + k0 + s*8];
            *(us8*)&sB[r*32 + sp*8] = val;
        }
        __syncthreads();

        s8v a0, a1, b0, b1, b2, b3;
        {
            int r = wm*32 + li;
            a0 = *(const s8v*)&sA[r*32 + ((g ^ ((r>>1)&3)))*8];
            int r2 = r + 16;
            a1 = *(const s8v*)&sA[r2*32 + ((g ^ ((r2>>1)&3)))*8];
        }
        {
            int r = wn*64 + li;
            b0 = *(const s8v*)&sB[r*32 + ((g ^ ((r>>1)&3)))*8];
            int r1 = r + 16;
            b1 = *(const s8v*)&sB[r1*32 + ((g ^ ((r1>>1)&3)))*8];
            int r2 = r + 32;
            b2 = *(const s8v*)&sB[r2*32 + ((g ^ ((r2>>1)&3)))*8];
            int r3 = r + 48;
            b3 = *(const s8v*)&sB[r3*32 + ((g ^ ((r3>>1)&3)))*8];
        }
        acc[0][0] = __builtin_amdgcn_mfma_f32_16x16x32_bf16(a0, b0, acc[0][0], 0, 0, 0);
        acc[0][1] = __builtin_amdgcn_mfma_f32_16x16x32_bf16(a0, b1, acc[0][1], 0, 0, 0);
        acc[0][2] = __builtin_amdgcn_mfma_f32_16x16x32_bf16(a0, b2, acc[0][2], 0, 0, 0);
        acc[0][3] = __builtin_amdgcn_mfma_f32_16x16x32_bf16(a0, b3, acc[0][3], 0, 0, 0);
        acc[1][0] = __builtin_amdgcn_mfma_f32_16x16x32_bf16(a1, b0, acc[1][0], 0, 0, 0);
        acc[1][1] = __builtin_amdgcn_mfma_f32_16x16x32_bf16(a1, b1, acc[1][1], 0, 0, 0);
        acc[1][2] = __builtin_amdgcn_mfma_f32_16x16x32_bf16(a1, b2, acc[1][2], 0, 0, 0);
        acc[1][3] = __builtin_amdgcn_mfma_f32_16x16x32_bf16(a1, b3, acc[1][3], 0, 0, 0);
        __syncthreads();
    }

    int hwMask = (1 << hwShift) - 1;
    #pragma unroll
    for (int i = 0; i < 2; ++i) {
        #pragma unroll
        for (int j = 0; j < 4; ++j) {
            #pragma unroll
            for (int r = 0; r < 4; ++r) {
                int co = co0 + wm*32 + i*16 + g*4 + r;
                int p  = p0 + wn*64 + j*16 + li;
                int nimg = p >> hwShift, sphw = p & hwMask;
                float v = acc[i][j][r];
                if (sc) v = v * sc[co] + bi[co];
                else    v = fmaxf(v, 0.f);
                out[(((size_t)(n0 + nimg)*Co + co) << hwShift) + sphw] = f2b(v);
            }
        }
    }
}

// ---------------- per-row (64-elem) mean via wave reduce ----------------
template<typename T>
__global__ void row_mean64(const T* __restrict__ in, float* __restrict__ out, int rows) {
    int w = (blockIdx.x*blockDim.x + threadIdx.x) >> 6;
    int lane = threadIdx.x & 63;
    if (w >= rows) return;
    float v = tof(in[(size_t)w*64 + lane]);
    #pragma unroll
    for (int off = 32; off > 0; off >>= 1) v += __shfl_down(v, off, 64);
    if (lane == 0) out[w] = v * (1.f/64.f);
}

// ---------------- classifier head ----------------
__global__ void head_sigmoid(const float* __restrict__ m, const float* __restrict__ cw,
                             const float* __restrict__ cb, float* __restrict__ out0,
                             float* __restrict__ out1, int Nrows) {
    int idx = blockIdx.x*blockDim.x + threadIdx.x;
    if (idx >= Nrows*20) return;
    int o = idx % 20, n = idx / 20;
    const float* mp = m + (size_t)n*1024;
    const float* wp = cw + (size_t)o*1024;
    float s = cb[o];
    for (int c=0;c<1024;++c) s += mp[c]*wp[c];
    float v = 1.f/(1.f+expf(-s));
    out0[idx] = v;
    if (out1) out1[idx] = v;
}

// ---------------- cam ----------------
__global__ void cam_kernel(const float* __restrict__ act, const float* __restrict__ cw,
                           const float* __restrict__ cb, float* __restrict__ cam, int N) {
    int idx = blockIdx.x*blockDim.x + threadIdx.x;
    if (idx >= N*20*64) return;
    int p = idx & 63; int o = (idx>>6) % 20; int n = idx / 1280;
    const float* a = act + (size_t)n*1024*64 + p;
    const float* wp = cw + (size_t)o*1024;
    float s = cb[o];
    for (int c=0;c<1024;++c) s += a[c*64]*wp[c];
    cam[idx] = 1.f/(1.f+expf(-s));
}

// ---------------- bilinear resize cam ----------------
__global__ void resize_cam(const float* __restrict__ cam, float* __restrict__ cs, int N) {
    int idx = blockIdx.x*blockDim.x + threadIdx.x;
    if (idx >= N*20*16384) return;
    int xo = idx & 127, yo = (idx>>7)&127;
    int bo = idx >> 14;
    float fy = (float)yo * (7.0f/127.0f);
    float fx = (float)xo * (7.0f/127.0f);
    int y0 = (int)floorf(fy); float wy = fy - (float)y0;
    int x0 = (int)floorf(fx); float wx = fx - (float)x0;
    if (y0 > 7) y0 = 7; if (y0 < 0) y0 = 0; int y1 = min(y0+1, 7);
    if (x0 > 7) x0 = 7; if (x0 < 0) x0 = 0; int x1 = min(x0+1, 7);
    const float* c = cam + (size_t)bo*64;
    float v = (1.f-wy)*((1.f-wx)*c[y0*8+x0] + wx*c[y0*8+x1])
            +      wy *((1.f-wx)*c[y1*8+x0] + wx*c[y1*8+x1]);
    cs[idx] = v;
}

// ---------------- wscore / hscore max reductions ----------------
__global__ void score_maxred(const float* __restrict__ cs, float* __restrict__ wsc,
                             float* __restrict__ hsc, int N) {
    int idx = blockIdx.x*blockDim.x + threadIdx.x;
    int total = N*20*128;
    if (idx >= 2*total) return;
    if (idx < total) {
        int wcol = idx % 128; int bo = idx / 128;
        const float* p = cs + (size_t)bo*16384 + wcol;
        float mv = -1e30f;
        for (int h=0; h<128; ++h) mv = fmaxf(mv, p[h*128]);
        wsc[idx] = mv;
    } else {
        int i = idx - total;
        int hrow = i % 128; int bo = i / 128;
        const float* p = cs + (size_t)bo*16384 + hrow*128;
        float mv = -1e30f;
        for (int w_=0; w_<128; ++w_) mv = fmaxf(mv, p[w_]);
        hsc[i] = mv;
    }
}

// ---------------- stable top-4 of 20 per batch ----------------
__global__ void topk4(const float* __restrict__ gs, int* __restrict__ top, int N) {
    int n = threadIdx.x;
    if (n >= N) return;
    const float* g = gs + n*20;
    bool used[20];
    for (int i=0;i<20;++i) used[i]=false;
    for (int t=0;t<4;++t) {
        int bi = -1; float bv = -1e30f;
        for (int i=0;i<20;++i) {
            if (!used[i] && g[i] > bv) { bv = g[i]; bi = i; }
        }
        used[bi] = true;
        top[n*4+t] = bi;
    }
}

// ---------------- gather top rows + norm01 ----------------
__global__ void gather_norm(const float* __restrict__ wsc, const float* __restrict__ hsc,
                            const int* __restrict__ top, float* __restrict__ xs,
                            float* __restrict__ ysn, int N) {
    int r = blockIdx.x;
    int axis = r / (N*4); int row = r % (N*4);
    int b = row / 4;
    int cls = top[row];
    const float* src = (axis==0 ? wsc : hsc) + ((size_t)b*20 + cls)*128;
    int t = threadIdx.x;
    float v = src[t];
    __shared__ float smn[128], smx[128];
    smn[t] = v; smx[t] = v;
    __syncthreads();
    for (int off=64; off>0; off>>=1) {
        if (t < off) { smn[t] = fminf(smn[t], smn[t+off]); smx[t] = fmaxf(smx[t], smx[t+off]); }
        __syncthreads();
    }
    float mn = smn[0], mx = smx[0];
    float outv;
    if (mx == mn) outv = v / (mx == 0.f ? 1.f : mx);
    else          outv = (v - mn) / (mx - mn);
    (axis==0 ? xs : ysn)[row*128 + t] = outv;
}

// ---------------- obj_loc ----------------
__global__ void objloc(const float* __restrict__ xs, const float* __restrict__ ysn,
                       int* __restrict__ box, int N) {
    int i = threadIdx.x;
    if (i >= 2*N*4) return;
    int axis = i / (N*4); int row = i % (N*4);
    const float* s = (axis ? ysn : xs) + (size_t)row*128;
    const int S = 128, minsize = 16;
    int pos[127]; int ncross = 0;
    int prev = sgnf(s[0] - 0.5f);
    for (int k=1; k<S; ++k) {
        int cur = sgnf(s[k] - 0.5f);
        int d = cur - prev; if (d < 0) d = -d;
        if (d == 2) pos[ncross++] = k-1;
        prev = cur;
    }
    float m = -1e30f;
    for (int k=0; k<S; ++k) m = fmaxf(m, s[k]);
    int zmin = 0, zmax = S, bestkey = -2;
    int a = 0;
    for (int j=0; j<=ncross; ++j) {
        int bnd = (j < ncross) ? pos[j] : S;
        float sm = -1e30f;
        for (int k=a; k<bnd; ++k) sm = fmaxf(sm, s[k]);
        int len = bnd - a;
        int key = (sm == m) ? len : -1;
        if (key > bestkey) { bestkey = key; zmin = a; zmax = bnd; }
        a = bnd;
    }
    bool need = (zmax - zmin) <= minsize;
    int pad = minsize - (zmax - zmin);
    int cp = (pad + 1) >> 1;
    bool c1 = need && (zmin > cp) && (S - zmax > pad);
    if (c1) { zmin = zmin - cp + 1; zmax = zmax + cp; }
    bool c2 = need && (zmin < cp);
    if (c2) { zmin = 0; zmax = minsize; }
    bool c3 = need && (S - zmax < cp);
    if (c3) { zmin = S - minsize + 1; zmax = S; }
    if (ncross == 0) { zmin = minsize; zmax = 112; }
    if (axis == 0) { box[row] = zmin; box[32+row] = zmax; }
    else           { box[64+row] = zmin; box[96+row] = zmax; }
}

// ---------------- crop + bilinear resize ----------------
__global__ void crop_resize_k(const float* __restrict__ x, const int* __restrict__ box,
                              float* __restrict__ lin, int N) {
    int idx = blockIdx.x*blockDim.x + threadIdx.x;
    if (idx >= N*4*3*16384) return;
    int xo = idx & 127, yo = (idx>>7)&127;
    int c  = (idx>>14) % 3;
    int r  = idx / 49152;
    int b  = r / 4;
    int cx1 = box[r],    cx2 = box[32+r];
    int cy1 = box[64+r], cy2 = box[96+r];
    float fy = (float)cy1 + (float)(yo * (cy2 - 1 - cy1)) / 127.0f;
    float fx = (float)cx1 + (float)(xo * (cx2 - 1 - cx1)) / 127.0f;
    float wy = fy - floorf(fy);
    float wx = fx - floorf(fx);
    int y0 = min(max((int)floorf(fy), 0), 127); int y1 = min(y0 + 1, 127);
    int x0 = min(max((int)floorf(fx), 0), 127); int x1 = min(x0 + 1, 127);
    const float* img = x + ((size_t)b*3 + c)*16384;
    float v = (1.f-wy)*((1.f-wx)*img[y0*128+x0] + wx*img[y0*128+x1])
            +      wy *((1.f-wx)*img[y1*128+x0] + wx*img[y1*128+x1]);
    lin[idx] = v;
}

// ---------------- local_stream = max over TOPN ----------------
__global__ void local_stream_max(const float* __restrict__ loc, float* __restrict__ out, int N) {
    int idx = threadIdx.x;
    if (idx >= N*20) return;
    int o = idx % 20, b = idx / 20;
    float mv = -1e30f;
    for (int t=0; t<4; ++t) mv = fmaxf(mv, loc[((size_t)(b*4+t))*20 + o]);
    out[idx] = mv;
}

// ---------------- f32 conv stack (round-7 verified config) ----------------
static void run_stack_f32(const float* input, int n,
                          const float* c1w, const float* bng, const float* bnb,
                          const float* bnm, const float* bnv,
                          const float* w1, const float* w2, const float* w3, const float* w4,
                          float* bufA, float* bufB, float* act, hipStream_t stream) {
    float* w3out = bufB + (size_t)n*512*256*2;
    conv7_bn_tiled<<<4*4*8*n, 256, 0, stream>>>(input, c1w, bng, bnb, bnm, bnv, bufA, n);
    conv3_tiled<1,16,16,16,8,512,24,true><<<4*4*8*n, 512, 0, stream>>>(bufA, w1, bufB, n, 64, 128, 64,64, 64,64, 0);
    conv3_tiled<2,8,8,32,8,256,20,true><<<4*4*8*n, 256, 0, stream>>>(bufB, w2, bufA, n, 128, 256, 64,64, 32,32, 0);
    {
        dim3 grid(2*2*16*n, 2);
        conv3_tiled<2,8,8,32,8,256,20,false><<<grid, 256, 0, stream>>>(bufA, w3, bufB, n, 256, 512, 32,32, 16,16, 128);
        int L = n*512*256;
        reduce_relu<<<(L/4+255)/256, 256, 0, stream>>>(bufB, w3out, L, 2);
    }
    {
        dim3 grid(1*1*32*n, 4);
        conv3_tiled<2,8,8,32,8,256,20,false><<<grid, 256, 0, stream>>>(w3out, w4, bufA, n, 512, 1024, 16,16, 8,8, 128);
        int L = n*1024*64;
        reduce_relu<<<(L/4+255)/256, 256, 0, stream>>>(bufA, act, L, 4);
    }
}

// ---------------- launcher ----------------
extern "C" void kernel_launch(void* const* d_in, const int* in_sizes, int n_in,
                              void* d_out_, int out_size, void* d_ws, size_t ws_size,
                              hipStream_t stream) {
    const float* x    = (const float*)d_in[0];
    const float* c1w  = (const float*)d_in[1];
    const float* bng  = (const float*)d_in[2];
    const float* bnb  = (const float*)d_in[3];
    const float* bnm  = (const float*)d_in[4];
    const float* bnv  = (const float*)d_in[5];
    const float* w1   = (const float*)d_in[6];
    const float* w2   = (const float*)d_in[7];
    const float* w3   = (const float*)d_in[8];
    const float* w4   = (const float*)d_in[9];
    const float* clsw = (const float*)d_in[10];
    const float* clsb = (const float*)d_in[11];
    float* dout = (float*)d_out_;

    float* out_gs = dout + 0;
    float* out_ls = dout + 160;
    float* out_cs = dout + 320;
    float* out_ws = dout + 2621760;
    float* out_hs = dout + 2642240;
    float* out_li = dout + 2662720;

    const size_t NEED = 101662720ull;
    if (ws_size >= NEED) {
        char* wsb = (char*)d_ws;
        ushort* wb1 = (ushort*)(wsb + 0);
        ushort* wb2 = (ushort*)(wsb + 147456);
        ushort* wb3 = (ushort*)(wsb + 737280);
        ushort* wb4 = (ushort*)(wsb + 3096576);
        ushort* R1  = (ushort*)(wsb + 12533760);
        ushort* R2  = (ushort*)(wsb + 29310976);
        ushort* BR  = (ushort*)(wsb + 62865408);
        float* gA   = (float*)(wsb + 62865408);
        float* gB   = (float*)(wsb + 62865408 + 8388608);
        float* gact = (float*)(wsb + 62865408 + 25165824);
        char* smb = wsb + 100614144;
        float* gmean = (float*)(smb);
        float* gst   = (float*)(smb + 32768);
        float* cam   = (float*)(smb + 33408);
        int*   top   = (int*)  (smb + 74368);
        float* xs    = (float*)(smb + 74496);
        float* ysn   = (float*)(smb + 90880);
        int*   box   = (int*)  (smb + 107264);
        float* lmean = (float*)(smb + 107776);
        float* locf  = (float*)(smb + 238848);
        ushort* wb7  = (ushort*)(smb + 262144);   // 20480 B
        float* bns   = (float*)(smb + 282624);    // 256 B
        float* bnb2  = (float*)(smb + 282880);    // 256 B

        wcast<<<288,256,0,stream>>>(w1, wb1, 73728);
        wcast<<<1152,256,0,stream>>>(w2, wb2, 294912);
        wcast<<<4608,256,0,stream>>>(w3, wb3, 1179648);
        wcast<<<18432,256,0,stream>>>(w4, wb4, 4718592);
        wcast7<<<40,256,0,stream>>>(c1w, wb7);
        bnprep<<<1,64,0,stream>>>(bng, bnb, bnm, bnv, bns, bnb2);

        // ---- global branch (f32, feeds discrete decisions) ----
        run_stack_f32(x, 8, c1w, bng, bnb, bnm, bnv, w1, w2, w3, w4, gA, gB, gact, stream);
        row_mean64<float><<<2048,256,0,stream>>>(gact, gmean, 8192);
        head_sigmoid<<<1,256,0,stream>>>(gmean, clsw, clsb, gst, out_gs, 8);
        cam_kernel<<<40,256,0,stream>>>(gact, clsw, clsb, cam, 8);
        resize_cam<<<10240,256,0,stream>>>(cam, out_cs, 8);
        score_maxred<<<160,256,0,stream>>>(out_cs, out_ws, out_hs, 8);
        topk4<<<1,64,0,stream>>>(gst, top, 8);
        gather_norm<<<64,128,0,stream>>>(out_ws, out_hs, top, xs, ysn, 8);
        objloc<<<1,64,0,stream>>>(xs, ysn, box, 8);
        crop_resize_k<<<6144,256,0,stream>>>(x, box, out_li, 8);

        // ---- local branch (bf16 MFMA throughout) ----
        // conv1 via GEMM: 2 chunks of 16 images, K=160, BN epilogue
        for (int c = 0; c < 2; ++c) {
            im2row7<<<5120,256,0,stream>>>(out_li, BR, c*16, 65536);
            gemm_conv<<<512,256,0,stream>>>(wb7, BR, R1, 64, 160, 65536, 64, 12, c*16, bns, bnb2);
        }
        // w1: 64->128 @64x64 s1
        for (int c = 0; c < 4; ++c) {
            im2row_k<<<9216,256,0,stream>>>(R1, BR, c*8, 32768, 64, 64, 64, 64, 64, 1, 576);
            gemm_conv<<<512,256,0,stream>>>(wb1, BR, R2, 128, 576, 32768, 128, 12, c*8, nullptr, nullptr);
        }
        // w2: 128->256, 64->32 s2
        for (int c = 0; c < 2; ++c) {
            im2row_k<<<9216,256,0,stream>>>(R2, BR, c*16, 16384, 128, 64, 64, 32, 32, 2, 1152);
            gemm_conv<<<512,256,0,stream>>>(wb2, BR, R1, 256, 1152, 16384, 256, 10, c*16, nullptr, nullptr);
        }
        // w3: 256->512, 32->16 s2
        im2row_k<<<9216,256,0,stream>>>(R1, BR, 0, 8192, 256, 32, 32, 16, 16, 2, 2304);
        gemm_conv<<<512,256,0,stream>>>(wb3, BR, R2, 512, 2304, 8192, 512, 8, 0, nullptr, nullptr);
        // w4: 512->1024, 16->8 s2
        im2row_k<<<4608,256,0,stream>>>(R2, BR, 0, 2048, 512, 16, 16, 8, 8, 2, 4608);
        gemm_conv<<<256,256,0,stream>>>(wb4, BR, R1, 1024, 4608, 2048, 1024, 6, 0, nullptr, nullptr);

        row_mean64<ushort><<<8192,256,0,stream>>>(R1, lmean, 32768);
        head_sigmoid<<<3,256,0,stream>>>(lmean, clsw, clsb, locf, (float*)nullptr, 32);
        local_stream_max<<<1,256,0,stream>>>(locf, out_ls, 8);
    } else {
        // -------- f32 fallback --------
        float* ws = (float*)d_ws;
        float* bufA  = ws + 0;
        float* bufB  = ws + 2097152;
        float* act   = ws + 6291456;
        float* gmean = ws + 6815744;
        float* gst   = ws + 6823936;
        float* cam   = ws + 6824096;
        int*   top   = (int*)(ws + 6834336);
        float* xs    = ws + 6834368;
        float* ysn   = ws + 6838464;
        int*   box   = (int*)(ws + 6842560);
        float* lmean = ws + 6842688;
        float* locf  = ws + 6875456;

        run_stack_f32(x, 8, c1w, bng, bnb, bnm, bnv, w1, w2, w3, w4, bufA, bufB, act, stream);
        row_mean64<float><<<2048,256,0,stream>>>(act, gmean, 8192);
        head_sigmoid<<<1,256,0,stream>>>(gmean, clsw, clsb, gst, out_gs, 8);
        cam_kernel<<<40,256,0,stream>>>(act, clsw, clsb, cam, 8);
        resize_cam<<<10240,256,0,stream>>>(cam, out_cs, 8);
        score_maxred<<<160,256,0,stream>>>(out_cs, out_ws, out_hs, 8);
        topk4<<<1,64,0,stream>>>(gst, top, 8);
        gather_norm<<<64,128,0,stream>>>(out_ws, out_hs, top, xs, ysn, 8);
        objloc<<<1,64,0,stream>>>(xs, ysn, box, 8);
        crop_resize_k<<<6144,256,0,stream>>>(x, box, out_li, 8);

        for (int c = 0; c < 4; ++c) {
            const float* lin_c = out_li + (size_t)c*8*3*16384;
            run_stack_f32(lin_c, 8, c1w, bng, bnb, bnm, bnv, w1, w2, w3, w4, bufA, bufB, act, stream);
            row_mean64<float><<<2048,256,0,stream>>>(act, lmean + c*8192, 8192);
        }
        head_sigmoid<<<3,256,0,stream>>>(lmean, clsw, clsb, locf, (float*)nullptr, 32);
        local_stream_max<<<1,256,0,stream>>>(locf, out_ls, 8);
    }
}

// Round 10
// 1460.122 us; speedup vs baseline: 1.1337x; 1.0198x over previous
//
#include <hip/hip_runtime.h>
#include <hip/hip_bf16.h>

// ---------------- helpers ----------------
__device__ __forceinline__ int sgnf(float v){ return (v>0.f)-(v<0.f); }
__device__ __forceinline__ ushort f2b(float f){ __hip_bfloat16 h = __float2bfloat16(f); return __builtin_bit_cast(ushort, h); }
__device__ __forceinline__ float  b2f(ushort u){ __hip_bfloat16 h = __builtin_bit_cast(__hip_bfloat16, u); return __bfloat162float(h); }
__device__ __forceinline__ float  tof(float v){ return v; }
__device__ __forceinline__ float  tof(ushort v){ return b2f(v); }

typedef short  s8v  __attribute__((ext_vector_type(8)));
typedef ushort us8  __attribute__((ext_vector_type(8)));
typedef float  f4v  __attribute__((ext_vector_type(4)));

// =====================================================================
// f32 tiled 3x3 conv (verified 2x4 tile).
// RELU=true: full conv + relu. RELU=false: K-split partial (raw, slab y).
// =====================================================================
template<int STRIDE, int TH, int TW, int CO_T, int CI_T, int NT, int P, bool RELU>
__global__ __launch_bounds__(NT) void conv3_tiled(
    const float* __restrict__ in, const float* __restrict__ w, float* __restrict__ out,
    int N, int Ci, int Co, int Hi, int Wi, int Ho, int Wo, int ciLen)
{
    constexpr int NSP   = (TH/2)*(TW/4);
    constexpr int IT_H  = (TH-1)*STRIDE + 3;
    constexpr int IT_W  = (TW-1)*STRIDE + 3;
    constexpr int IN_ELEMS = CI_T*IT_H*IT_W;
    constexpr int W_ELEMS  = CI_T*CO_T*9;
    static_assert(NSP*CO_T == NT, "thread count mismatch");
    static_assert(IT_W <= P, "pitch too small");

    __shared__ __align__(16) float s_in[CI_T*IT_H*P];
    __shared__ __align__(16) float s_w[CI_T*CO_T*12];

    int bx = blockIdx.x;
    const int spxn = Wo/TW, spyn = Ho/TH, cog = Co/CO_T;
    const int sxb = bx % spxn; bx /= spxn;
    const int syb = bx % spyn; bx /= spyn;
    const int cg  = bx % cog;  const int n = bx / cog;
    const int tx0 = sxb*TW, ty0 = syb*TH, co0 = cg*CO_T;

    const int ciStart = RELU ? 0 : blockIdx.y * ciLen;
    const int ciEnd   = RELU ? Ci : ciStart + ciLen;
    if (!RELU) out += (size_t)blockIdx.y * N * Co * Ho * Wo;

    const int tid = threadIdx.x;
    const int sp  = tid % NSP;
    const int co  = tid / NSP;
    const int sy  = (sp / (TW/4)) * 2;
    const int sx  = (sp % (TW/4)) * 4;

    const int y_in0 = ty0*STRIDE - 1, x_in0 = tx0*STRIDE - 1;
    const float* in_n = in + (size_t)n*Ci*Hi*Wi;

    float acc[2][4] = {{0.f,0.f,0.f,0.f},{0.f,0.f,0.f,0.f}};

    for (int ci0 = ciStart; ci0 < ciEnd; ci0 += CI_T) {
        for (int idx = tid; idx < IN_ELEMS; idx += NT) {
            int ci  = idx / (IT_H*IT_W);
            int rem = idx - ci*(IT_H*IT_W);
            int iy  = rem / IT_W;
            int ix  = rem - iy*IT_W;
            int gy = y_in0 + iy, gx = x_in0 + ix;
            float v = 0.f;
            if ((unsigned)gy < (unsigned)Hi && (unsigned)gx < (unsigned)Wi)
                v = in_n[(size_t)(ci0+ci)*Hi*Wi + gy*Wi + gx];
            s_in[ci*(IT_H*P) + iy*P + ix] = v;
        }
        for (int idx = tid; idx < W_ELEMS; idx += NT) {
            int ci  = idx / (CO_T*9);
            int rem = idx - ci*(CO_T*9);
            int c   = rem / 9, k = rem - c*9;
            s_w[(ci*CO_T + c)*12 + k] = w[((size_t)(co0+c)*Ci + (ci0+ci))*9 + k];
        }
        __syncthreads();

        #pragma unroll
        for (int ci = 0; ci < CI_T; ++ci) {
            const float* wp = &s_w[(ci*CO_T + co)*12];
            float4 wa = *(const float4*)wp;
            float4 wb = *(const float4*)(wp+4);
            float w8  = wp[8];
            float wr[9] = {wa.x,wa.y,wa.z,wa.w, wb.x,wb.y,wb.z,wb.w, w8};
            const float* ip = &s_in[ci*(IT_H*P)];

            if constexpr (STRIDE == 1) {
                #pragma unroll
                for (int pr = 0; pr < 4; ++pr) {
                    const float* row = ip + (sy+pr)*P + sx;
                    float4 a = *(const float4*)row;
                    float2 b = *(const float2*)(row+4);
                    float e[6] = {a.x,a.y,a.z,a.w,b.x,b.y};
                    #pragma unroll
                    for (int ky = 0; ky < 3; ++ky) {
                        int ry = pr - ky;
                        if (ry == 0 || ry == 1) {
                            #pragma unroll
                            for (int kx = 0; kx < 3; ++kx)
                                #pragma unroll
                                for (int rx = 0; rx < 4; ++rx)
                                    acc[ry][rx] += e[rx+kx] * wr[ky*3+kx];
                        }
                    }
                }
            } else {
                #pragma unroll
                for (int pr = 0; pr < 5; ++pr) {
                    const float* row = ip + (2*sy+pr)*P + 2*sx;
                    float4 a = *(const float4*)row;
                    float4 b = *(const float4*)(row+4);
                    float c8 = row[8];
                    float e[9] = {a.x,a.y,a.z,a.w,b.x,b.y,b.z,b.w,c8};
                    #pragma unroll
                    for (int ky = 0; ky < 3; ++ky) {
                        int ry2 = pr - ky;
                        if (ry2 == 0 || ry2 == 2) {
                            int ry = ry2 >> 1;
                            #pragma unroll
                            for (int kx = 0; kx < 3; ++kx)
                                #pragma unroll
                                for (int rx = 0; rx < 4; ++rx)
                                    acc[ry][rx] += e[2*rx+kx] * wr[ky*3+kx];
                        }
                    }
                }
            }
        }
        __syncthreads();
    }

    float* op = out + ((size_t)n*Co + co0 + co)*Ho*Wo + (size_t)(ty0+sy)*Wo + (tx0+sx);
    #pragma unroll
    for (int ry=0; ry<2; ++ry) {
        float4 v;
        if constexpr (RELU) {
            v.x = fmaxf(acc[ry][0], 0.f); v.y = fmaxf(acc[ry][1], 0.f);
            v.z = fmaxf(acc[ry][2], 0.f); v.w = fmaxf(acc[ry][3], 0.f);
        } else {
            v.x = acc[ry][0]; v.y = acc[ry][1]; v.z = acc[ry][2]; v.w = acc[ry][3];
        }
        *(float4*)(op + (size_t)ry*Wo) = v;
    }
}

// ---------------- sum K partial slabs + relu (out may alias slab 0) ----------------
__global__ void reduce_relu(const float* __restrict__ part, float* __restrict__ out,
                            int L, int KS) {
    int i = (blockIdx.x*blockDim.x + threadIdx.x) * 4;
    if (i >= L) return;
    float4 s = *(const float4*)&part[i];
    for (int k = 1; k < KS; ++k) {
        float4 p = *(const float4*)&part[(size_t)k*L + i];
        s.x += p.x; s.y += p.y; s.z += p.z; s.w += p.w;
    }
    s.x = fmaxf(s.x, 0.f); s.y = fmaxf(s.y, 0.f);
    s.z = fmaxf(s.z, 0.f); s.w = fmaxf(s.w, 0.f);
    *(float4*)&out[i] = s;
}

// =====================================================================
// 7x7 s2 p3 conv + BN, f32 (global branch)
// =====================================================================
__global__ __launch_bounds__(256) void conv7_bn_tiled(
    const float* __restrict__ x, const float* __restrict__ w,
    const float* __restrict__ gamma, const float* __restrict__ beta,
    const float* __restrict__ mean, const float* __restrict__ var,
    float* __restrict__ out, int N)
{
    constexpr int IT = 37;
    constexpr int P  = 38;
    constexpr int NT = 256;
    constexpr int IN_ELEMS = 3*IT*IT;
    constexpr int W_ELEMS  = 8*3*49;

    __shared__ __align__(16) float s_in[3*IT*P];
    __shared__ __align__(16) float s_w[8*3*7*8];

    int bx = blockIdx.x;
    const int sxb = bx % 4; bx /= 4;
    const int syb = bx % 4; bx /= 4;
    const int cg  = bx % 8; const int n = bx / 8;
    const int tx0 = sxb*16, ty0 = syb*16, co0 = cg*8;

    const int tid = threadIdx.x;
    const int sp  = tid % 32;
    const int co  = tid / 32;
    const int sy  = (sp / 4) * 2;
    const int sx  = (sp % 4) * 4;

    const int y_in0 = ty0*2 - 3, x_in0 = tx0*2 - 3;
    const float* x_n = x + (size_t)n*3*16384;

    for (int idx = tid; idx < IN_ELEMS; idx += NT) {
        int ci  = idx / (IT*IT);
        int rem = idx - ci*(IT*IT);
        int iy  = rem / IT;
        int ix  = rem - iy*IT;
        int gy = y_in0 + iy, gx = x_in0 + ix;
        float v = 0.f;
        if ((unsigned)gy < 128u && (unsigned)gx < 128u)
            v = x_n[(size_t)ci*16384 + gy*128 + gx];
        s_in[ci*(IT*P) + iy*P + ix] = v;
    }
    for (int idx = tid; idx < W_ELEMS; idx += NT) {
        int c   = idx / 147;
        int rem = idx - c*147;
        int ci  = rem / 49;
        int rem2= rem - ci*49;
        int ky  = rem2 / 7, kx = rem2 - ky*7;
        s_w[((c*3 + ci)*7 + ky)*8 + kx] = w[(size_t)(co0+c)*147 + ci*49 + ky*7 + kx];
    }
    __syncthreads();

    float acc[2][4] = {{0.f,0.f,0.f,0.f},{0.f,0.f,0.f,0.f}};
    const int c0 = 2*sx;
    #pragma unroll 1
    for (int ci = 0; ci < 3; ++ci) {
        const float* ip = &s_in[ci*(IT*P)];
        #pragma unroll
        for (int pr = 0; pr < 9; ++pr) {
            const float* row = ip + (2*sy+pr)*P + c0;
            float2 q0 = *(const float2*)(row+0);
            float2 q1 = *(const float2*)(row+2);
            float2 q2 = *(const float2*)(row+4);
            float2 q3 = *(const float2*)(row+6);
            float2 q4 = *(const float2*)(row+8);
            float2 q5 = *(const float2*)(row+10);
            float  e12 = row[12];
            float e[13] = {q0.x,q0.y,q1.x,q1.y,q2.x,q2.y,q3.x,q3.y,q4.x,q4.y,q5.x,q5.y,e12};
            #pragma unroll
            for (int ry = 0; ry < 2; ++ry) {
                int ky = pr - 2*ry;
                if (ky >= 0 && ky < 7) {
                    const float* wrow = &s_w[((co*3 + ci)*7 + ky)*8];
                    float4 wa = *(const float4*)wrow;
                    float2 wbv = *(const float2*)(wrow+4);
                    float w6 = wrow[6];
                    float wk[7] = {wa.x,wa.y,wa.z,wa.w,wbv.x,wbv.y,w6};
                    #pragma unroll
                    for (int kx = 0; kx < 7; ++kx)
                        #pragma unroll
                        for (int rx = 0; rx < 4; ++rx)
                            acc[ry][rx] += e[2*rx+kx] * wk[kx];
                }
            }
        }
    }

    const int coo = co0 + co;
    float inv = gamma[coo] / sqrtf(var[coo] + 1e-5f);
    float mu = mean[coo], bb = beta[coo];
    float* op = out + ((size_t)n*64 + coo)*4096 + (size_t)(ty0+sy)*64 + (tx0+sx);
    #pragma unroll
    for (int ry=0; ry<2; ++ry) {
        float4 v;
        v.x = (acc[ry][0]-mu)*inv + bb; v.y = (acc[ry][1]-mu)*inv + bb;
        v.z = (acc[ry][2]-mu)*inv + bb; v.w = (acc[ry][3]-mu)*inv + bb;
        *(float4*)(op + (size_t)ry*64) = v;
    }
}

// ---------------- weight casts ----------------
__global__ void wcast(const float* __restrict__ src, ushort* __restrict__ dst, int n) {
    int i = blockIdx.x*blockDim.x + threadIdx.x;
    if (i < n) dst[i] = f2b(src[i]);
}
__global__ void wcast7(const float* __restrict__ src, ushort* __restrict__ dst) {
    int i = blockIdx.x*blockDim.x + threadIdx.x;
    if (i >= 64*160) return;
    int co = i / 160, k = i - co*160;
    dst[i] = (k < 147) ? f2b(src[co*147 + k]) : (ushort)0;
}
__global__ void bnprep(const float* __restrict__ g, const float* __restrict__ be,
                       const float* __restrict__ mu, const float* __restrict__ va,
                       float* __restrict__ s, float* __restrict__ b) {
    int i = threadIdx.x;
    if (i >= 64) return;
    float sv = g[i] / sqrtf(va[i] + 1e-5f);
    s[i] = sv;
    b[i] = be[i] - mu[i]*sv;
}

// ---------------- im2row (bf16 NCHW -> Brow[p][k]) for 3x3 ----------------
__global__ void im2row_k(const ushort* __restrict__ in, ushort* __restrict__ Brow,
                         int n0, int NN, int Ci, int Hi, int Wi, int Ho, int Wo,
                         int stride, int K) {
    int idx = blockIdx.x*blockDim.x + threadIdx.x;
    int K8 = K >> 3;
    if (idx >= NN * K8) return;
    int ks = idx % K8;
    int p  = idx / K8;
    int xo = p % Wo; int t = p / Wo; int yo = t % Ho; int nl = t / Ho;
    const ushort* ip = in + (size_t)(n0 + nl)*Ci*Hi*Wi;
    int y0 = yo*stride - 1, x0 = xo*stride - 1;
    us8 v;
    #pragma unroll
    for (int j = 0; j < 8; ++j) {
        int k = ks*8 + j;
        int ci = k / 9, tt = k - ci*9;
        int ky = tt / 3, kx = tt - ky*3;
        int yi = y0 + ky, xi = x0 + kx;
        ushort val = 0;
        if ((unsigned)yi < (unsigned)Hi && (unsigned)xi < (unsigned)Wi)
            val = ip[(size_t)ci*Hi*Wi + yi*Wi + xi];
        v[j] = val;
    }
    *(us8*)&Brow[(size_t)p*K + ks*8] = v;
}

// ---------------- im2row for conv1 7x7 s2 p3: f32 input -> bf16 rows K=160 ----------------
__global__ void im2row7(const float* __restrict__ in, ushort* __restrict__ Brow,
                        int n0, int NN) {
    int idx = blockIdx.x*blockDim.x + threadIdx.x;
    if (idx >= NN * 20) return;
    int ks = idx % 20;
    int p  = idx / 20;
    int xo = p & 63; int t = p >> 6; int yo = t & 63; int nl = t >> 6;
    const float* ip = in + (size_t)(n0 + nl)*3*16384;
    int y0 = yo*2 - 3, x0 = xo*2 - 3;
    us8 v;
    #pragma unroll
    for (int j = 0; j < 8; ++j) {
        int k = ks*8 + j;
        ushort val = 0;
        if (k < 147) {
            int ci = k / 49, tt = k - ci*49;
            int ky = tt / 7, kx = tt - ky*7;
            int yi = y0 + ky, xi = x0 + kx;
            if ((unsigned)yi < 128u && (unsigned)xi < 128u)
                val = f2b(ip[(size_t)ci*16384 + yi*128 + xi]);
        }
        v[j] = val;
    }
    *(us8*)&Brow[(size_t)p*160 + ks*8] = v;
}

// ---------------- bf16 MFMA GEMM; epilogue relu (sc==null) or BN affine ----------------
__global__ __launch_bounds__(256) void gemm_conv(
    const ushort* __restrict__ A, const ushort* __restrict__ B,
    ushort* __restrict__ out,
    int M, int K, int NN, int Co, int hwShift, int n0,
    const float* __restrict__ sc, const float* __restrict__ bi)
{
    __shared__ __align__(16) ushort sA[64*32];
    __shared__ __align__(16) ushort sB[128*32];

    int bx = blockIdx.x;
    int mtiles = M >> 6;
    int mt = bx % mtiles;
    int nt = bx / mtiles;
    int co0 = mt << 6, p0 = nt << 7;
    int tid = threadIdx.x, lane = tid & 63, wave = tid >> 6;
    int wm = wave & 1, wn = wave >> 1;

    f4v acc[2][4];
    #pragma unroll
    for (int i=0;i<2;++i)
        #pragma unroll
        for (int j=0;j<4;++j)
            #pragma unroll
            for (int r=0;r<4;++r) acc[i][j][r] = 0.f;

    const int g  = lane >> 4;
    const int li = lane & 15;

    for (int k0 = 0; k0 < K; k0 += 32) {
        {
            int r = tid >> 2, s = tid & 3;
            int sp = s ^ ((r >> 1) & 3);
            us8 val = *(const us8*)&A[(size_t)(co0 + r)*K + k0 + s*8];
            *(us8*)&sA[r*32 + sp*8] = val;
        }
        #pragma unroll
        for (int h = 0; h < 2; ++h) {
            int slot = tid + h*256;
            int r = slot >> 2, s = slot & 3;
            int sp = s ^ ((r >> 1) & 3);
            us8 val = *(const us8*)&B[(size_t)(p0 + r)*K + k0 + s*8];
            *(us8*)&sB[r*32 + sp*8] = val;
        }
        __syncthreads();

        s8v a0, a1, b0, b1, b2, b3;
        {
            int r = wm*32 + li;
            a0 = *(const s8v*)&sA[r*32 + ((g ^ ((r>>1)&3)))*8];
            int r2 = r + 16;
            a1 = *(const s8v*)&sA[r2*32 + ((g ^ ((r2>>1)&3)))*8];
        }
        {
            int r = wn*64 + li;
            b0 = *(const s8v*)&sB[r*32 + ((g ^ ((r>>1)&3)))*8];
            int r1 = r + 16;
            b1 = *(const s8v*)&sB[r1*32 + ((g ^ ((r1>>1)&3)))*8];
            int r2 = r + 32;
            b2 = *(const s8v*)&sB[r2*32 + ((g ^ ((r2>>1)&3)))*8];
            int r3 = r + 48;
            b3 = *(const s8v*)&sB[r3*32 + ((g ^ ((r3>>1)&3)))*8];
        }
        acc[0][0] = __builtin_amdgcn_mfma_f32_16x16x32_bf16(a0, b0, acc[0][0], 0, 0, 0);
        acc[0][1] = __builtin_amdgcn_mfma_f32_16x16x32_bf16(a0, b1, acc[0][1], 0, 0, 0);
        acc[0][2] = __builtin_amdgcn_mfma_f32_16x16x32_bf16(a0, b2, acc[0][2], 0, 0, 0);
        acc[0][3] = __builtin_amdgcn_mfma_f32_16x16x32_bf16(a0, b3, acc[0][3], 0, 0, 0);
        acc[1][0] = __builtin_amdgcn_mfma_f32_16x16x32_bf16(a1, b0, acc[1][0], 0, 0, 0);
        acc[1][1] = __builtin_amdgcn_mfma_f32_16x16x32_bf16(a1, b1, acc[1][1], 0, 0, 0);
        acc[1][2] = __builtin_amdgcn_mfma_f32_16x16x32_bf16(a1, b2, acc[1][2], 0, 0, 0);
        acc[1][3] = __builtin_amdgcn_mfma_f32_16x16x32_bf16(a1, b3, acc[1][3], 0, 0, 0);
        __syncthreads();
    }

    int hwMask = (1 << hwShift) - 1;
    #pragma unroll
    for (int i = 0; i < 2; ++i) {
        #pragma unroll
        for (int j = 0; j < 4; ++j) {
            #pragma unroll
            for (int r = 0; r < 4; ++r) {
                int co = co0 + wm*32 + i*16 + g*4 + r;
                int p  = p0 + wn*64 + j*16 + li;
                int nimg = p >> hwShift, sphw = p & hwMask;
                float v = acc[i][j][r];
                if (sc) v = v * sc[co] + bi[co];
                else    v = fmaxf(v, 0.f);
                out[(((size_t)(n0 + nimg)*Co + co) << hwShift) + sphw] = f2b(v);
            }
        }
    }
}

// ---------------- per-row (64-elem) mean via wave reduce ----------------
template<typename T>
__global__ void row_mean64(const T* __restrict__ in, float* __restrict__ out, int rows) {
    int w = (blockIdx.x*blockDim.x + threadIdx.x) >> 6;
    int lane = threadIdx.x & 63;
    if (w >= rows) return;
    float v = tof(in[(size_t)w*64 + lane]);
    #pragma unroll
    for (int off = 32; off > 0; off >>= 1) v += __shfl_down(v, off, 64);
    if (lane == 0) out[w] = v * (1.f/64.f);
}

// ---------------- classifier head ----------------
__global__ void head_sigmoid(const float* __restrict__ m, const float* __restrict__ cw,
                             const float* __restrict__ cb, float* __restrict__ out0,
                             float* __restrict__ out1, int Nrows) {
    int idx = blockIdx.x*blockDim.x + threadIdx.x;
    if (idx >= Nrows*20) return;
    int o = idx % 20, n = idx / 20;
    const float* mp = m + (size_t)n*1024;
    const float* wp = cw + (size_t)o*1024;
    float s = cb[o];
    for (int c=0;c<1024;++c) s += mp[c]*wp[c];
    float v = 1.f/(1.f+expf(-s));
    out0[idx] = v;
    if (out1) out1[idx] = v;
}

// ---------------- cam ----------------
__global__ void cam_kernel(const float* __restrict__ act, const float* __restrict__ cw,
                           const float* __restrict__ cb, float* __restrict__ cam, int N) {
    int idx = blockIdx.x*blockDim.x + threadIdx.x;
    if (idx >= N*20*64) return;
    int p = idx & 63; int o = (idx>>6) % 20; int n = idx / 1280;
    const float* a = act + (size_t)n*1024*64 + p;
    const float* wp = cw + (size_t)o*1024;
    float s = cb[o];
    for (int c=0;c<1024;++c) s += a[c*64]*wp[c];
    cam[idx] = 1.f/(1.f+expf(-s));
}

// ---------------- bilinear resize cam ----------------
__global__ void resize_cam(const float* __restrict__ cam, float* __restrict__ cs, int N) {
    int idx = blockIdx.x*blockDim.x + threadIdx.x;
    if (idx >= N*20*16384) return;
    int xo = idx & 127, yo = (idx>>7)&127;
    int bo = idx >> 14;
    float fy = (float)yo * (7.0f/127.0f);
    float fx = (float)xo * (7.0f/127.0f);
    int y0 = (int)floorf(fy); float wy = fy - (float)y0;
    int x0 = (int)floorf(fx); float wx = fx - (float)x0;
    if (y0 > 7) y0 = 7; if (y0 < 0) y0 = 0; int y1 = min(y0+1, 7);
    if (x0 > 7) x0 = 7; if (x0 < 0) x0 = 0; int x1 = min(x0+1, 7);
    const float* c = cam + (size_t)bo*64;
    float v = (1.f-wy)*((1.f-wx)*c[y0*8+x0] + wx*c[y0*8+x1])
            +      wy *((1.f-wx)*c[y1*8+x0] + wx*c[y1*8+x1]);
    cs[idx] = v;
}

// ---------------- wscore / hscore max reductions ----------------
__global__ void score_maxred(const float* __restrict__ cs, float* __restrict__ wsc,
                             float* __restrict__ hsc, int N) {
    int idx = blockIdx.x*blockDim.x + threadIdx.x;
    int total = N*20*128;
    if (idx >= 2*total) return;
    if (idx < total) {
        int wcol = idx % 128; int bo = idx / 128;
        const float* p = cs + (size_t)bo*16384 + wcol;
        float mv = -1e30f;
        for (int h=0; h<128; ++h) mv = fmaxf(mv, p[h*128]);
        wsc[idx] = mv;
    } else {
        int i = idx - total;
        int hrow = i % 128; int bo = i / 128;
        const float* p = cs + (size_t)bo*16384 + hrow*128;
        float mv = -1e30f;
        for (int w_=0; w_<128; ++w_) mv = fmaxf(mv, p[w_]);
        hsc[i] = mv;
    }
}

// ---------------- stable top-4 of 20 per batch ----------------
__global__ void topk4(const float* __restrict__ gs, int* __restrict__ top, int N) {
    int n = threadIdx.x;
    if (n >= N) return;
    const float* g = gs + n*20;
    bool used[20];
    for (int i=0;i<20;++i) used[i]=false;
    for (int t=0;t<4;++t) {
        int bi = -1; float bv = -1e30f;
        for (int i=0;i<20;++i) {
            if (!used[i] && g[i] > bv) { bv = g[i]; bi = i; }
        }
        used[bi] = true;
        top[n*4+t] = bi;
    }
}

// ---------------- gather top rows + norm01 ----------------
__global__ void gather_norm(const float* __restrict__ wsc, const float* __restrict__ hsc,
                            const int* __restrict__ top, float* __restrict__ xs,
                            float* __restrict__ ysn, int N) {
    int r = blockIdx.x;
    int axis = r / (N*4); int row = r % (N*4);
    int b = row / 4;
    int cls = top[row];
    const float* src = (axis==0 ? wsc : hsc) + ((size_t)b*20 + cls)*128;
    int t = threadIdx.x;
    float v = src[t];
    __shared__ float smn[128], smx[128];
    smn[t] = v; smx[t] = v;
    __syncthreads();
    for (int off=64; off>0; off>>=1) {
        if (t < off) { smn[t] = fminf(smn[t], smn[t+off]); smx[t] = fmaxf(smx[t], smx[t+off]); }
        __syncthreads();
    }
    float mn = smn[0], mx = smx[0];
    float outv;
    if (mx == mn) outv = v / (mx == 0.f ? 1.f : mx);
    else          outv = (v - mn) / (mx - mn);
    (axis==0 ? xs : ysn)[row*128 + t] = outv;
}

// ---------------- obj_loc ----------------
__global__ void objloc(const float* __restrict__ xs, const float* __restrict__ ysn,
                       int* __restrict__ box, int N) {
    int i = threadIdx.x;
    if (i >= 2*N*4) return;
    int axis = i / (N*4); int row = i % (N*4);
    const float* s = (axis ? ysn : xs) + (size_t)row*128;
    const int S = 128, minsize = 16;
    int pos[127]; int ncross = 0;
    int prev = sgnf(s[0] - 0.5f);
    for (int k=1; k<S; ++k) {
        int cur = sgnf(s[k] - 0.5f);
        int d = cur - prev; if (d < 0) d = -d;
        if (d == 2) pos[ncross++] = k-1;
        prev = cur;
    }
    float m = -1e30f;
    for (int k=0; k<S; ++k) m = fmaxf(m, s[k]);
    int zmin = 0, zmax = S, bestkey = -2;
    int a = 0;
    for (int j=0; j<=ncross; ++j) {
        int bnd = (j < ncross) ? pos[j] : S;
        float sm = -1e30f;
        for (int k=a; k<bnd; ++k) sm = fmaxf(sm, s[k]);
        int len = bnd - a;
        int key = (sm == m) ? len : -1;
        if (key > bestkey) { bestkey = key; zmin = a; zmax = bnd; }
        a = bnd;
    }
    bool need = (zmax - zmin) <= minsize;
    int pad = minsize - (zmax - zmin);
    int cp = (pad + 1) >> 1;
    bool c1 = need && (zmin > cp) && (S - zmax > pad);
    if (c1) { zmin = zmin - cp + 1; zmax = zmax + cp; }
    bool c2 = need && (zmin < cp);
    if (c2) { zmin = 0; zmax = minsize; }
    bool c3 = need && (S - zmax < cp);
    if (c3) { zmin = S - minsize + 1; zmax = S; }
    if (ncross == 0) { zmin = minsize; zmax = 112; }
    if (axis == 0) { box[row] = zmin; box[32+row] = zmax; }
    else           { box[64+row] = zmin; box[96+row] = zmax; }
}

// ---------------- crop + bilinear resize ----------------
__global__ void crop_resize_k(const float* __restrict__ x, const int* __restrict__ box,
                              float* __restrict__ lin, int N) {
    int idx = blockIdx.x*blockDim.x + threadIdx.x;
    if (idx >= N*4*3*16384) return;
    int xo = idx & 127, yo = (idx>>7)&127;
    int c  = (idx>>14) % 3;
    int r  = idx / 49152;
    int b  = r / 4;
    int cx1 = box[r],    cx2 = box[32+r];
    int cy1 = box[64+r], cy2 = box[96+r];
    float fy = (float)cy1 + (float)(yo * (cy2 - 1 - cy1)) / 127.0f;
    float fx = (float)cx1 + (float)(xo * (cx2 - 1 - cx1)) / 127.0f;
    float wy = fy - floorf(fy);
    float wx = fx - floorf(fx);
    int y0 = min(max((int)floorf(fy), 0), 127); int y1 = min(y0 + 1, 127);
    int x0 = min(max((int)floorf(fx), 0), 127); int x1 = min(x0 + 1, 127);
    const float* img = x + ((size_t)b*3 + c)*16384;
    float v = (1.f-wy)*((1.f-wx)*img[y0*128+x0] + wx*img[y0*128+x1])
            +      wy *((1.f-wx)*img[y1*128+x0] + wx*img[y1*128+x1]);
    lin[idx] = v;
}

// ---------------- local_stream = max over TOPN ----------------
__global__ void local_stream_max(const float* __restrict__ loc, float* __restrict__ out, int N) {
    int idx = threadIdx.x;
    if (idx >= N*20) return;
    int o = idx % 20, b = idx / 20;
    float mv = -1e30f;
    for (int t=0; t<4; ++t) mv = fmaxf(mv, loc[((size_t)(b*4+t))*20 + o]);
    out[idx] = mv;
}

// ---------------- f32 conv stack: K-split everywhere, 8 rounds/block ----------------
// Region O must be >= 33.6MB. Layout (byte offsets into O):
//   conv7 out C7 = O+25165824 (8.4MB)   [dead after w1]
//   w1 out  W1O = O+0        (16.8MB)   [dead after w2]
//   w2 part P2  = O+16777216 (2x8.4MB) -> W2O = slab0 (O+16777216)
//   w3 part P3  = O+0        (4x4.19MB)-> W3O = slab0 (O+0)
//   w4 part P4  = O+16777216 (8x2.1MB) -> ACT = slab0 (O+16777216)
static void run_stack_f32(const float* input, int n,
                          const float* c1w, const float* bng, const float* bnb,
                          const float* bnm, const float* bnv,
                          const float* w1, const float* w2, const float* w3, const float* w4,
                          char* O, float** act_out, hipStream_t stream) {
    float* C7  = (float*)(O + 25165824);
    float* W1O = (float*)(O + 0);
    float* P2  = (float*)(O + 16777216);
    float* P3  = (float*)(O + 0);
    float* P4  = (float*)(O + 16777216);

    conv7_bn_tiled<<<4*4*8*n, 256, 0, stream>>>(input, c1w, bng, bnb, bnm, bnv, C7, n);
    conv3_tiled<1,16,16,16,8,512,24,true><<<4*4*8*n, 512, 0, stream>>>(C7, w1, W1O, n, 64, 128, 64,64, 64,64, 0);
    // w2 KS=2: 8 rounds/block, grid (1024,2)
    {
        dim3 grid(4*4*8*n, 2);
        conv3_tiled<2,8,8,32,8,256,20,false><<<grid, 256, 0, stream>>>(W1O, w2, P2, n, 128, 256, 64,64, 32,32, 64);
        int L = n*256*1024;
        reduce_relu<<<(L/4+255)/256, 256, 0, stream>>>(P2, P2, L, 2);
    }
    // w3 KS=4: 8 rounds/block, grid (512,4)
    {
        dim3 grid(2*2*16*n, 4);
        conv3_tiled<2,8,8,32,8,256,20,false><<<grid, 256, 0, stream>>>(P2, w3, P3, n, 256, 512, 32,32, 16,16, 64);
        int L = n*512*256;
        reduce_relu<<<(L/4+255)/256, 256, 0, stream>>>(P3, P3, L, 4);
    }
    // w4 KS=8: 8 rounds/block, grid (256,8)
    {
        dim3 grid(1*1*32*n, 8);
        conv3_tiled<2,8,8,32,8,256,20,false><<<grid, 256, 0, stream>>>(P3, w4, P4, n, 512, 1024, 16,16, 8,8, 64);
        int L = n*1024*64;
        reduce_relu<<<(L/4+255)/256, 256, 0, stream>>>(P4, P4, L, 8);
    }
    *act_out = P4;   // ACT = slab0
}

// ---------------- launcher ----------------
extern "C" void kernel_launch(void* const* d_in, const int* in_sizes, int n_in,
                              void* d_out_, int out_size, void* d_ws, size_t ws_size,
                              hipStream_t stream) {
    const float* x    = (const float*)d_in[0];
    const float* c1w  = (const float*)d_in[1];
    const float* bng  = (const float*)d_in[2];
    const float* bnb  = (const float*)d_in[3];
    const float* bnm  = (const float*)d_in[4];
    const float* bnv  = (const float*)d_in[5];
    const float* w1   = (const float*)d_in[6];
    const float* w2   = (const float*)d_in[7];
    const float* w3   = (const float*)d_in[8];
    const float* w4   = (const float*)d_in[9];
    const float* clsw = (const float*)d_in[10];
    const float* clsb = (const float*)d_in[11];
    float* dout = (float*)d_out_;

    float* out_gs = dout + 0;
    float* out_ls = dout + 160;
    float* out_cs = dout + 320;
    float* out_ws = dout + 2621760;
    float* out_hs = dout + 2642240;
    float* out_li = dout + 2662720;

    const size_t NEED = 101662720ull;
    if (ws_size >= NEED) {
        char* wsb = (char*)d_ws;
        ushort* wb1 = (ushort*)(wsb + 0);
        ushort* wb2 = (ushort*)(wsb + 147456);
        ushort* wb3 = (ushort*)(wsb + 737280);
        ushort* wb4 = (ushort*)(wsb + 3096576);
        ushort* R1  = (ushort*)(wsb + 12533760);
        ushort* R2  = (ushort*)(wsb + 29310976);
        ushort* BR  = (ushort*)(wsb + 62865408);
        char*   GO  = wsb + 62865408;                 // global f32 region (37.75MB, overlaps BR)
        char* smb = wsb + 100614144;
        float* gmean = (float*)(smb);
        float* gst   = (float*)(smb + 32768);
        float* cam   = (float*)(smb + 33408);
        int*   top   = (int*)  (smb + 74368);
        float* xs    = (float*)(smb + 74496);
        float* ysn   = (float*)(smb + 90880);
        int*   box   = (int*)  (smb + 107264);
        float* lmean = (float*)(smb + 107776);
        float* locf  = (float*)(smb + 238848);
        ushort* wb7  = (ushort*)(smb + 262144);
        float* bns   = (float*)(smb + 282624);
        float* bnb2  = (float*)(smb + 282880);

        wcast<<<288,256,0,stream>>>(w1, wb1, 73728);
        wcast<<<1152,256,0,stream>>>(w2, wb2, 294912);
        wcast<<<4608,256,0,stream>>>(w3, wb3, 1179648);
        wcast<<<18432,256,0,stream>>>(w4, wb4, 4718592);
        wcast7<<<40,256,0,stream>>>(c1w, wb7);
        bnprep<<<1,64,0,stream>>>(bng, bnb, bnm, bnv, bns, bnb2);

        // ---- global branch (f32, feeds discrete decisions) ----
        float* gact = nullptr;
        run_stack_f32(x, 8, c1w, bng, bnb, bnm, bnv, w1, w2, w3, w4, GO, &gact, stream);
        row_mean64<float><<<2048,256,0,stream>>>(gact, gmean, 8192);
        head_sigmoid<<<1,256,0,stream>>>(gmean, clsw, clsb, gst, out_gs, 8);
        cam_kernel<<<40,256,0,stream>>>(gact, clsw, clsb, cam, 8);
        resize_cam<<<10240,256,0,stream>>>(cam, out_cs, 8);
        score_maxred<<<160,256,0,stream>>>(out_cs, out_ws, out_hs, 8);
        topk4<<<1,64,0,stream>>>(gst, top, 8);
        gather_norm<<<64,128,0,stream>>>(out_ws, out_hs, top, xs, ysn, 8);
        objloc<<<1,64,0,stream>>>(xs, ysn, box, 8);
        crop_resize_k<<<6144,256,0,stream>>>(x, box, out_li, 8);

        // ---- local branch (bf16 MFMA throughout) ----
        for (int c = 0; c < 2; ++c) {
            im2row7<<<5120,256,0,stream>>>(out_li, BR, c*16, 65536);
            gemm_conv<<<512,256,0,stream>>>(wb7, BR, R1, 64, 160, 65536, 64, 12, c*16, bns, bnb2);
        }
        for (int c = 0; c < 4; ++c) {
            im2row_k<<<9216,256,0,stream>>>(R1, BR, c*8, 32768, 64, 64, 64, 64, 64, 1, 576);
            gemm_conv<<<512,256,0,stream>>>(wb1, BR, R2, 128, 576, 32768, 128, 12, c*8, nullptr, nullptr);
        }
        for (int c = 0; c < 2; ++c) {
            im2row_k<<<9216,256,0,stream>>>(R2, BR, c*16, 16384, 128, 64, 64, 32, 32, 2, 1152);
            gemm_conv<<<512,256,0,stream>>>(wb2, BR, R1, 256, 1152, 16384, 256, 10, c*16, nullptr, nullptr);
        }
        im2row_k<<<9216,256,0,stream>>>(R1, BR, 0, 8192, 256, 32, 32, 16, 16, 2, 2304);
        gemm_conv<<<512,256,0,stream>>>(wb3, BR, R2, 512, 2304, 8192, 512, 8, 0, nullptr, nullptr);
        im2row_k<<<4608,256,0,stream>>>(R2, BR, 0, 2048, 512, 16, 16, 8, 8, 2, 4608);
        gemm_conv<<<256,256,0,stream>>>(wb4, BR, R1, 1024, 4608, 2048, 1024, 6, 0, nullptr, nullptr);

        row_mean64<ushort><<<8192,256,0,stream>>>(R1, lmean, 32768);
        head_sigmoid<<<3,256,0,stream>>>(lmean, clsw, clsb, locf, (float*)nullptr, 32);
        local_stream_max<<<1,256,0,stream>>>(locf, out_ls, 8);
    } else {
        // -------- f32 fallback (new-layout stack; needs ~35MB) --------
        char* O = (char*)d_ws;
        char* smb = O + 33554432;
        float* gmean = (float*)(smb);
        float* gst   = (float*)(smb + 32768);
        float* cam   = (float*)(smb + 33408);
        int*   top   = (int*)  (smb + 74368);
        float* xs    = (float*)(smb + 74496);
        float* ysn   = (float*)(smb + 90880);
        int*   box   = (int*)  (smb + 107264);
        float* lmean = (float*)(smb + 107776);
        float* locf  = (float*)(smb + 238848);

        float* act = nullptr;
        run_stack_f32(x, 8, c1w, bng, bnb, bnm, bnv, w1, w2, w3, w4, O, &act, stream);
        row_mean64<float><<<2048,256,0,stream>>>(act, gmean, 8192);
        head_sigmoid<<<1,256,0,stream>>>(gmean, clsw, clsb, gst, out_gs, 8);
        cam_kernel<<<40,256,0,stream>>>(act, clsw, clsb, cam, 8);
        resize_cam<<<10240,256,0,stream>>>(cam, out_cs, 8);
        score_maxred<<<160,256,0,stream>>>(out_cs, out_ws, out_hs, 8);
        topk4<<<1,64,0,stream>>>(gst, top, 8);
        gather_norm<<<64,128,0,stream>>>(out_ws, out_hs, top, xs, ysn, 8);
        objloc<<<1,64,0,stream>>>(xs, ysn, box, 8);
        crop_resize_k<<<6144,256,0,stream>>>(x, box, out_li, 8);

        for (int c = 0; c < 4; ++c) {
            const float* lin_c = out_li + (size_t)c*8*3*16384;
            run_stack_f32(lin_c, 8, c1w, bng, bnb, bnm, bnv, w1, w2, w3, w4, O, &act, stream);
            row_mean64<float><<<2048,256,0,stream>>>(act, lmean + c*8192, 8192);
        }
        head_sigmoid<<<3,256,0,stream>>>(lmean, clsw, clsb, locf, (float*)nullptr, 32);
        local_stream_max<<<1,256,0,stream>>>(locf, out_ls, 8);
    }
}

// Round 11
// 1453.445 us; speedup vs baseline: 1.1389x; 1.0046x over previous
//
#include <hip/hip_runtime.h>
#include <hip/hip_bf16.h>

// ---------------- helpers ----------------
__device__ __forceinline__ int sgnf(float v){ return (v>0.f)-(v<0.f); }
__device__ __forceinline__ ushort f2b(float f){ __hip_bfloat16 h = __float2bfloat16(f); return __builtin_bit_cast(ushort, h); }
__device__ __forceinline__ float  b2f(ushort u){ __hip_bfloat16 h = __builtin_bit_cast(__hip_bfloat16, u); return __bfloat162float(h); }
__device__ __forceinline__ float  tof(float v){ return v; }
__device__ __forceinline__ float  tof(ushort v){ return b2f(v); }

typedef short  s8v  __attribute__((ext_vector_type(8)));
typedef ushort us8  __attribute__((ext_vector_type(8)));
typedef float  f4v  __attribute__((ext_vector_type(4)));

#if __has_builtin(__builtin_amdgcn_global_load_lds)
#define USE_GLL 1
typedef __attribute__((address_space(1))) void gvoid;
typedef __attribute__((address_space(3))) void lvoid;
#else
#define USE_GLL 0
#endif

// =====================================================================
// f32 tiled 3x3 conv (verified 2x4 tile).
// RELU=true: full conv + relu. RELU=false: K-split partial (raw, slab y).
// =====================================================================
template<int STRIDE, int TH, int TW, int CO_T, int CI_T, int NT, int P, bool RELU>
__global__ __launch_bounds__(NT) void conv3_tiled(
    const float* __restrict__ in, const float* __restrict__ w, float* __restrict__ out,
    int N, int Ci, int Co, int Hi, int Wi, int Ho, int Wo, int ciLen)
{
    constexpr int NSP   = (TH/2)*(TW/4);
    constexpr int IT_H  = (TH-1)*STRIDE + 3;
    constexpr int IT_W  = (TW-1)*STRIDE + 3;
    constexpr int IN_ELEMS = CI_T*IT_H*IT_W;
    constexpr int W_ELEMS  = CI_T*CO_T*9;
    static_assert(NSP*CO_T == NT, "thread count mismatch");
    static_assert(IT_W <= P, "pitch too small");

    __shared__ __align__(16) float s_in[CI_T*IT_H*P];
    __shared__ __align__(16) float s_w[CI_T*CO_T*12];

    int bx = blockIdx.x;
    const int spxn = Wo/TW, spyn = Ho/TH, cog = Co/CO_T;
    const int sxb = bx % spxn; bx /= spxn;
    const int syb = bx % spyn; bx /= spyn;
    const int cg  = bx % cog;  const int n = bx / cog;
    const int tx0 = sxb*TW, ty0 = syb*TH, co0 = cg*CO_T;

    const int ciStart = RELU ? 0 : blockIdx.y * ciLen;
    const int ciEnd   = RELU ? Ci : ciStart + ciLen;
    if (!RELU) out += (size_t)blockIdx.y * N * Co * Ho * Wo;

    const int tid = threadIdx.x;
    const int sp  = tid % NSP;
    const int co  = tid / NSP;
    const int sy  = (sp / (TW/4)) * 2;
    const int sx  = (sp % (TW/4)) * 4;

    const int y_in0 = ty0*STRIDE - 1, x_in0 = tx0*STRIDE - 1;
    const float* in_n = in + (size_t)n*Ci*Hi*Wi;

    float acc[2][4] = {{0.f,0.f,0.f,0.f},{0.f,0.f,0.f,0.f}};

    for (int ci0 = ciStart; ci0 < ciEnd; ci0 += CI_T) {
        for (int idx = tid; idx < IN_ELEMS; idx += NT) {
            int ci  = idx / (IT_H*IT_W);
            int rem = idx - ci*(IT_H*IT_W);
            int iy  = rem / IT_W;
            int ix  = rem - iy*IT_W;
            int gy = y_in0 + iy, gx = x_in0 + ix;
            float v = 0.f;
            if ((unsigned)gy < (unsigned)Hi && (unsigned)gx < (unsigned)Wi)
                v = in_n[(size_t)(ci0+ci)*Hi*Wi + gy*Wi + gx];
            s_in[ci*(IT_H*P) + iy*P + ix] = v;
        }
        for (int idx = tid; idx < W_ELEMS; idx += NT) {
            int ci  = idx / (CO_T*9);
            int rem = idx - ci*(CO_T*9);
            int c   = rem / 9, k = rem - c*9;
            s_w[(ci*CO_T + c)*12 + k] = w[((size_t)(co0+c)*Ci + (ci0+ci))*9 + k];
        }
        __syncthreads();

        #pragma unroll
        for (int ci = 0; ci < CI_T; ++ci) {
            const float* wp = &s_w[(ci*CO_T + co)*12];
            float4 wa = *(const float4*)wp;
            float4 wb = *(const float4*)(wp+4);
            float w8  = wp[8];
            float wr[9] = {wa.x,wa.y,wa.z,wa.w, wb.x,wb.y,wb.z,wb.w, w8};
            const float* ip = &s_in[ci*(IT_H*P)];

            if constexpr (STRIDE == 1) {
                #pragma unroll
                for (int pr = 0; pr < 4; ++pr) {
                    const float* row = ip + (sy+pr)*P + sx;
                    float4 a = *(const float4*)row;
                    float2 b = *(const float2*)(row+4);
                    float e[6] = {a.x,a.y,a.z,a.w,b.x,b.y};
                    #pragma unroll
                    for (int ky = 0; ky < 3; ++ky) {
                        int ry = pr - ky;
                        if (ry == 0 || ry == 1) {
                            #pragma unroll
                            for (int kx = 0; kx < 3; ++kx)
                                #pragma unroll
                                for (int rx = 0; rx < 4; ++rx)
                                    acc[ry][rx] += e[rx+kx] * wr[ky*3+kx];
                        }
                    }
                }
            } else {
                #pragma unroll
                for (int pr = 0; pr < 5; ++pr) {
                    const float* row = ip + (2*sy+pr)*P + 2*sx;
                    float4 a = *(const float4*)row;
                    float4 b = *(const float4*)(row+4);
                    float c8 = row[8];
                    float e[9] = {a.x,a.y,a.z,a.w,b.x,b.y,b.z,b.w,c8};
                    #pragma unroll
                    for (int ky = 0; ky < 3; ++ky) {
                        int ry2 = pr - ky;
                        if (ry2 == 0 || ry2 == 2) {
                            int ry = ry2 >> 1;
                            #pragma unroll
                            for (int kx = 0; kx < 3; ++kx)
                                #pragma unroll
                                for (int rx = 0; rx < 4; ++rx)
                                    acc[ry][rx] += e[2*rx+kx] * wr[ky*3+kx];
                        }
                    }
                }
            }
        }
        __syncthreads();
    }

    float* op = out + ((size_t)n*Co + co0 + co)*Ho*Wo + (size_t)(ty0+sy)*Wo + (tx0+sx);
    #pragma unroll
    for (int ry=0; ry<2; ++ry) {
        float4 v;
        if constexpr (RELU) {
            v.x = fmaxf(acc[ry][0], 0.f); v.y = fmaxf(acc[ry][1], 0.f);
            v.z = fmaxf(acc[ry][2], 0.f); v.w = fmaxf(acc[ry][3], 0.f);
        } else {
            v.x = acc[ry][0]; v.y = acc[ry][1]; v.z = acc[ry][2]; v.w = acc[ry][3];
        }
        *(float4*)(op + (size_t)ry*Wo) = v;
    }
}

// ---------------- sum K partial slabs + relu (out may alias slab 0) ----------------
__global__ void reduce_relu(const float* __restrict__ part, float* __restrict__ out,
                            int L, int KS) {
    int i = (blockIdx.x*blockDim.x + threadIdx.x) * 4;
    if (i >= L) return;
    float4 s = *(const float4*)&part[i];
    for (int k = 1; k < KS; ++k) {
        float4 p = *(const float4*)&part[(size_t)k*L + i];
        s.x += p.x; s.y += p.y; s.z += p.z; s.w += p.w;
    }
    s.x = fmaxf(s.x, 0.f); s.y = fmaxf(s.y, 0.f);
    s.z = fmaxf(s.z, 0.f); s.w = fmaxf(s.w, 0.f);
    *(float4*)&out[i] = s;
}

// =====================================================================
// 7x7 s2 p3 conv + BN, f32 (global branch)
// =====================================================================
__global__ __launch_bounds__(256) void conv7_bn_tiled(
    const float* __restrict__ x, const float* __restrict__ w,
    const float* __restrict__ gamma, const float* __restrict__ beta,
    const float* __restrict__ mean, const float* __restrict__ var,
    float* __restrict__ out, int N)
{
    constexpr int IT = 37;
    constexpr int P  = 38;
    constexpr int NT = 256;
    constexpr int IN_ELEMS = 3*IT*IT;
    constexpr int W_ELEMS  = 8*3*49;

    __shared__ __align__(16) float s_in[3*IT*P];
    __shared__ __align__(16) float s_w[8*3*7*8];

    int bx = blockIdx.x;
    const int sxb = bx % 4; bx /= 4;
    const int syb = bx % 4; bx /= 4;
    const int cg  = bx % 8; const int n = bx / 8;
    const int tx0 = sxb*16, ty0 = syb*16, co0 = cg*8;

    const int tid = threadIdx.x;
    const int sp  = tid % 32;
    const int co  = tid / 32;
    const int sy  = (sp / 4) * 2;
    const int sx  = (sp % 4) * 4;

    const int y_in0 = ty0*2 - 3, x_in0 = tx0*2 - 3;
    const float* x_n = x + (size_t)n*3*16384;

    for (int idx = tid; idx < IN_ELEMS; idx += NT) {
        int ci  = idx / (IT*IT);
        int rem = idx - ci*(IT*IT);
        int iy  = rem / IT;
        int ix  = rem - iy*IT;
        int gy = y_in0 + iy, gx = x_in0 + ix;
        float v = 0.f;
        if ((unsigned)gy < 128u && (unsigned)gx < 128u)
            v = x_n[(size_t)ci*16384 + gy*128 + gx];
        s_in[ci*(IT*P) + iy*P + ix] = v;
    }
    for (int idx = tid; idx < W_ELEMS; idx += NT) {
        int c   = idx / 147;
        int rem = idx - c*147;
        int ci  = rem / 49;
        int rem2= rem - ci*49;
        int ky  = rem2 / 7, kx = rem2 - ky*7;
        s_w[((c*3 + ci)*7 + ky)*8 + kx] = w[(size_t)(co0+c)*147 + ci*49 + ky*7 + kx];
    }
    __syncthreads();

    float acc[2][4] = {{0.f,0.f,0.f,0.f},{0.f,0.f,0.f,0.f}};
    const int c0 = 2*sx;
    #pragma unroll 1
    for (int ci = 0; ci < 3; ++ci) {
        const float* ip = &s_in[ci*(IT*P)];
        #pragma unroll
        for (int pr = 0; pr < 9; ++pr) {
            const float* row = ip + (2*sy+pr)*P + c0;
            float2 q0 = *(const float2*)(row+0);
            float2 q1 = *(const float2*)(row+2);
            float2 q2 = *(const float2*)(row+4);
            float2 q3 = *(const float2*)(row+6);
            float2 q4 = *(const float2*)(row+8);
            float2 q5 = *(const float2*)(row+10);
            float  e12 = row[12];
            float e[13] = {q0.x,q0.y,q1.x,q1.y,q2.x,q2.y,q3.x,q3.y,q4.x,q4.y,q5.x,q5.y,e12};
            #pragma unroll
            for (int ry = 0; ry < 2; ++ry) {
                int ky = pr - 2*ry;
                if (ky >= 0 && ky < 7) {
                    const float* wrow = &s_w[((co*3 + ci)*7 + ky)*8];
                    float4 wa = *(const float4*)wrow;
                    float2 wbv = *(const float2*)(wrow+4);
                    float w6 = wrow[6];
                    float wk[7] = {wa.x,wa.y,wa.z,wa.w,wbv.x,wbv.y,w6};
                    #pragma unroll
                    for (int kx = 0; kx < 7; ++kx)
                        #pragma unroll
                        for (int rx = 0; rx < 4; ++rx)
                            acc[ry][rx] += e[2*rx+kx] * wk[kx];
                }
            }
        }
    }

    const int coo = co0 + co;
    float inv = gamma[coo] / sqrtf(var[coo] + 1e-5f);
    float mu = mean[coo], bb = beta[coo];
    float* op = out + ((size_t)n*64 + coo)*4096 + (size_t)(ty0+sy)*64 + (tx0+sx);
    #pragma unroll
    for (int ry=0; ry<2; ++ry) {
        float4 v;
        v.x = (acc[ry][0]-mu)*inv + bb; v.y = (acc[ry][1]-mu)*inv + bb;
        v.z = (acc[ry][2]-mu)*inv + bb; v.w = (acc[ry][3]-mu)*inv + bb;
        *(float4*)(op + (size_t)ry*64) = v;
    }
}

// ---------------- weight casts ----------------
__global__ void wcast(const float* __restrict__ src, ushort* __restrict__ dst, int n) {
    int i = blockIdx.x*blockDim.x + threadIdx.x;
    if (i < n) dst[i] = f2b(src[i]);
}
__global__ void wcast7(const float* __restrict__ src, ushort* __restrict__ dst) {
    int i = blockIdx.x*blockDim.x + threadIdx.x;
    if (i >= 64*160) return;
    int co = i / 160, k = i - co*160;
    dst[i] = (k < 147) ? f2b(src[co*147 + k]) : (ushort)0;
}
__global__ void bnprep(const float* __restrict__ g, const float* __restrict__ be,
                       const float* __restrict__ mu, const float* __restrict__ va,
                       float* __restrict__ s, float* __restrict__ b) {
    int i = threadIdx.x;
    if (i >= 64) return;
    float sv = g[i] / sqrtf(va[i] + 1e-5f);
    s[i] = sv;
    b[i] = be[i] - mu[i]*sv;
}

// ---------------- im2row (bf16 NCHW -> Brow[p][k]) for 3x3 ----------------
__global__ void im2row_k(const ushort* __restrict__ in, ushort* __restrict__ Brow,
                         int n0, int NN, int Ci, int Hi, int Wi, int Ho, int Wo,
                         int stride, int K) {
    int idx = blockIdx.x*blockDim.x + threadIdx.x;
    int K8 = K >> 3;
    if (idx >= NN * K8) return;
    int ks = idx % K8;
    int p  = idx / K8;
    int xo = p % Wo; int t = p / Wo; int yo = t % Ho; int nl = t / Ho;
    const ushort* ip = in + (size_t)(n0 + nl)*Ci*Hi*Wi;
    int y0 = yo*stride - 1, x0 = xo*stride - 1;
    us8 v;
    #pragma unroll
    for (int j = 0; j < 8; ++j) {
        int k = ks*8 + j;
        int ci = k / 9, tt = k - ci*9;
        int ky = tt / 3, kx = tt - ky*3;
        int yi = y0 + ky, xi = x0 + kx;
        ushort val = 0;
        if ((unsigned)yi < (unsigned)Hi && (unsigned)xi < (unsigned)Wi)
            val = ip[(size_t)ci*Hi*Wi + yi*Wi + xi];
        v[j] = val;
    }
    *(us8*)&Brow[(size_t)p*K + ks*8] = v;
}

// ---------------- im2row for conv1 7x7 s2 p3: f32 input -> bf16 rows K=160 ----------------
__global__ void im2row7(const float* __restrict__ in, ushort* __restrict__ Brow,
                        int n0, int NN) {
    int idx = blockIdx.x*blockDim.x + threadIdx.x;
    if (idx >= NN * 20) return;
    int ks = idx % 20;
    int p  = idx / 20;
    int xo = p & 63; int t = p >> 6; int yo = t & 63; int nl = t >> 6;
    const float* ip = in + (size_t)(n0 + nl)*3*16384;
    int y0 = yo*2 - 3, x0 = xo*2 - 3;
    us8 v;
    #pragma unroll
    for (int j = 0; j < 8; ++j) {
        int k = ks*8 + j;
        ushort val = 0;
        if (k < 147) {
            int ci = k / 49, tt = k - ci*49;
            int ky = tt / 7, kx = tt - ky*7;
            int yi = y0 + ky, xi = x0 + kx;
            if ((unsigned)yi < 128u && (unsigned)xi < 128u)
                val = f2b(ip[(size_t)ci*16384 + yi*128 + xi]);
        }
        v[j] = val;
    }
    *(us8*)&Brow[(size_t)p*160 + ks*8] = v;
}

// ---------------- bf16 MFMA GEMM; epilogue relu (sc==null) or BN affine ----------------
// Staging via global_load_lds (width 16): LDS dest is linear per wave,
// XOR swizzle applied on the GLOBAL source k-segment; read-side XOR unchanged.
__global__ __launch_bounds__(256) void gemm_conv(
    const ushort* __restrict__ A, const ushort* __restrict__ B,
    ushort* __restrict__ out,
    int M, int K, int NN, int Co, int hwShift, int n0,
    const float* __restrict__ sc, const float* __restrict__ bi)
{
    __shared__ __align__(16) ushort sA[64*32];
    __shared__ __align__(16) ushort sB[128*32];

    int bx = blockIdx.x;
    int mtiles = M >> 6;
    int mt = bx % mtiles;
    int nt = bx / mtiles;
    int co0 = mt << 6, p0 = nt << 7;
    int tid = threadIdx.x, lane = tid & 63, wave = tid >> 6;
    int wm = wave & 1, wn = wave >> 1;

    f4v acc[2][4];
    #pragma unroll
    for (int i=0;i<2;++i)
        #pragma unroll
        for (int j=0;j<4;++j)
            #pragma unroll
            for (int r=0;r<4;++r) acc[i][j][r] = 0.f;

    const int g  = lane >> 4;
    const int li = lane & 15;

    for (int k0 = 0; k0 < K; k0 += 32) {
#if USE_GLL
        {   // stage A: 64 rows x 32 cols; wave w fills rows 16w..16w+15 linearly
            int r = tid >> 2;
            int s = (lane & 3) ^ ((r >> 1) & 3);      // logical k-seg for this linear slot
            const ushort* gp = &A[(size_t)(co0 + r)*K + k0 + s*8];
            __builtin_amdgcn_global_load_lds((gvoid*)gp, (lvoid*)&sA[wave*512], 16, 0, 0);
        }
        #pragma unroll
        for (int h = 0; h < 2; ++h) {   // stage B: 128 rows
            int slot = tid + h*256;
            int r = slot >> 2;
            int s = (lane & 3) ^ ((r >> 1) & 3);
            const ushort* gp = &B[(size_t)(p0 + r)*K + k0 + s*8];
            __builtin_amdgcn_global_load_lds((gvoid*)gp, (lvoid*)&sB[(h*4 + wave)*512], 16, 0, 0);
        }
#else
        {
            int r = tid >> 2, s = tid & 3;
            int sp = s ^ ((r >> 1) & 3);
            us8 val = *(const us8*)&A[(size_t)(co0 + r)*K + k0 + s*8];
            *(us8*)&sA[r*32 + sp*8] = val;
        }
        #pragma unroll
        for (int h = 0; h < 2; ++h) {
            int slot = tid + h*256;
            int r = slot >> 2, s = slot & 3;
            int sp = s ^ ((r >> 1) & 3);
            us8 val = *(const us8*)&B[(size_t)(p0 + r)*K + k0 + s*8];
            *(us8*)&sB[r*32 + sp*8] = val;
        }
#endif
        __syncthreads();

        s8v a0, a1, b0, b1, b2, b3;
        {
            int r = wm*32 + li;
            a0 = *(const s8v*)&sA[r*32 + ((g ^ ((r>>1)&3)))*8];
            int r2 = r + 16;
            a1 = *(const s8v*)&sA[r2*32 + ((g ^ ((r2>>1)&3)))*8];
        }
        {
            int r = wn*64 + li;
            b0 = *(const s8v*)&sB[r*32 + ((g ^ ((r>>1)&3)))*8];
            int r1 = r + 16;
            b1 = *(const s8v*)&sB[r1*32 + ((g ^ ((r1>>1)&3)))*8];
            int r2 = r + 32;
            b2 = *(const s8v*)&sB[r2*32 + ((g ^ ((r2>>1)&3)))*8];
            int r3 = r + 48;
            b3 = *(const s8v*)&sB[r3*32 + ((g ^ ((r3>>1)&3)))*8];
        }
        acc[0][0] = __builtin_amdgcn_mfma_f32_16x16x32_bf16(a0, b0, acc[0][0], 0, 0, 0);
        acc[0][1] = __builtin_amdgcn_mfma_f32_16x16x32_bf16(a0, b1, acc[0][1], 0, 0, 0);
        acc[0][2] = __builtin_amdgcn_mfma_f32_16x16x32_bf16(a0, b2, acc[0][2], 0, 0, 0);
        acc[0][3] = __builtin_amdgcn_mfma_f32_16x16x32_bf16(a0, b3, acc[0][3], 0, 0, 0);
        acc[1][0] = __builtin_amdgcn_mfma_f32_16x16x32_bf16(a1, b0, acc[1][0], 0, 0, 0);
        acc[1][1] = __builtin_amdgcn_mfma_f32_16x16x32_bf16(a1, b1, acc[1][1], 0, 0, 0);
        acc[1][2] = __builtin_amdgcn_mfma_f32_16x16x32_bf16(a1, b2, acc[1][2], 0, 0, 0);
        acc[1][3] = __builtin_amdgcn_mfma_f32_16x16x32_bf16(a1, b3, acc[1][3], 0, 0, 0);
        __syncthreads();
    }

    int hwMask = (1 << hwShift) - 1;
    #pragma unroll
    for (int i = 0; i < 2; ++i) {
        #pragma unroll
        for (int j = 0; j < 4; ++j) {
            #pragma unroll
            for (int r = 0; r < 4; ++r) {
                int co = co0 + wm*32 + i*16 + g*4 + r;
                int p  = p0 + wn*64 + j*16 + li;
                int nimg = p >> hwShift, sphw = p & hwMask;
                float v = acc[i][j][r];
                if (sc) v = v * sc[co] + bi[co];
                else    v = fmaxf(v, 0.f);
                out[(((size_t)(n0 + nimg)*Co + co) << hwShift) + sphw] = f2b(v);
            }
        }
    }
}

// ---------------- per-row (64-elem) mean via wave reduce ----------------
template<typename T>
__global__ void row_mean64(const T* __restrict__ in, float* __restrict__ out, int rows) {
    int w = (blockIdx.x*blockDim.x + threadIdx.x) >> 6;
    int lane = threadIdx.x & 63;
    if (w >= rows) return;
    float v = tof(in[(size_t)w*64 + lane]);
    #pragma unroll
    for (int off = 32; off > 0; off >>= 1) v += __shfl_down(v, off, 64);
    if (lane == 0) out[w] = v * (1.f/64.f);
}

// ---------------- classifier head ----------------
__global__ void head_sigmoid(const float* __restrict__ m, const float* __restrict__ cw,
                             const float* __restrict__ cb, float* __restrict__ out0,
                             float* __restrict__ out1, int Nrows) {
    int idx = blockIdx.x*blockDim.x + threadIdx.x;
    if (idx >= Nrows*20) return;
    int o = idx % 20, n = idx / 20;
    const float* mp = m + (size_t)n*1024;
    const float* wp = cw + (size_t)o*1024;
    float s = cb[o];
    for (int c=0;c<1024;++c) s += mp[c]*wp[c];
    float v = 1.f/(1.f+expf(-s));
    out0[idx] = v;
    if (out1) out1[idx] = v;
}

// ---------------- cam ----------------
__global__ void cam_kernel(const float* __restrict__ act, const float* __restrict__ cw,
                           const float* __restrict__ cb, float* __restrict__ cam, int N) {
    int idx = blockIdx.x*blockDim.x + threadIdx.x;
    if (idx >= N*20*64) return;
    int p = idx & 63; int o = (idx>>6) % 20; int n = idx / 1280;
    const float* a = act + (size_t)n*1024*64 + p;
    const float* wp = cw + (size_t)o*1024;
    float s = cb[o];
    for (int c=0;c<1024;++c) s += a[c*64]*wp[c];
    cam[idx] = 1.f/(1.f+expf(-s));
}

// ---------------- bilinear resize cam ----------------
__global__ void resize_cam(const float* __restrict__ cam, float* __restrict__ cs, int N) {
    int idx = blockIdx.x*blockDim.x + threadIdx.x;
    if (idx >= N*20*16384) return;
    int xo = idx & 127, yo = (idx>>7)&127;
    int bo = idx >> 14;
    float fy = (float)yo * (7.0f/127.0f);
    float fx = (float)xo * (7.0f/127.0f);
    int y0 = (int)floorf(fy); float wy = fy - (float)y0;
    int x0 = (int)floorf(fx); float wx = fx - (float)x0;
    if (y0 > 7) y0 = 7; if (y0 < 0) y0 = 0; int y1 = min(y0+1, 7);
    if (x0 > 7) x0 = 7; if (x0 < 0) x0 = 0; int x1 = min(x0+1, 7);
    const float* c = cam + (size_t)bo*64;
    float v = (1.f-wy)*((1.f-wx)*c[y0*8+x0] + wx*c[y0*8+x1])
            +      wy *((1.f-wx)*c[y1*8+x0] + wx*c[y1*8+x1]);
    cs[idx] = v;
}

// ---------------- wscore / hscore max reductions ----------------
__global__ void score_maxred(const float* __restrict__ cs, float* __restrict__ wsc,
                             float* __restrict__ hsc, int N) {
    int idx = blockIdx.x*blockDim.x + threadIdx.x;
    int total = N*20*128;
    if (idx >= 2*total) return;
    if (idx < total) {
        int wcol = idx % 128; int bo = idx / 128;
        const float* p = cs + (size_t)bo*16384 + wcol;
        float mv = -1e30f;
        for (int h=0; h<128; ++h) mv = fmaxf(mv, p[h*128]);
        wsc[idx] = mv;
    } else {
        int i = idx - total;
        int hrow = i % 128; int bo = i / 128;
        const float* p = cs + (size_t)bo*16384 + hrow*128;
        float mv = -1e30f;
        for (int w_=0; w_<128; ++w_) mv = fmaxf(mv, p[w_]);
        hsc[i] = mv;
    }
}

// ---------------- stable top-4 of 20 per batch ----------------
__global__ void topk4(const float* __restrict__ gs, int* __restrict__ top, int N) {
    int n = threadIdx.x;
    if (n >= N) return;
    const float* g = gs + n*20;
    bool used[20];
    for (int i=0;i<20;++i) used[i]=false;
    for (int t=0;t<4;++t) {
        int bi = -1; float bv = -1e30f;
        for (int i=0;i<20;++i) {
            if (!used[i] && g[i] > bv) { bv = g[i]; bi = i; }
        }
        used[bi] = true;
        top[n*4+t] = bi;
    }
}

// ---------------- gather top rows + norm01 ----------------
__global__ void gather_norm(const float* __restrict__ wsc, const float* __restrict__ hsc,
                            const int* __restrict__ top, float* __restrict__ xs,
                            float* __restrict__ ysn, int N) {
    int r = blockIdx.x;
    int axis = r / (N*4); int row = r % (N*4);
    int b = row / 4;
    int cls = top[row];
    const float* src = (axis==0 ? wsc : hsc) + ((size_t)b*20 + cls)*128;
    int t = threadIdx.x;
    float v = src[t];
    __shared__ float smn[128], smx[128];
    smn[t] = v; smx[t] = v;
    __syncthreads();
    for (int off=64; off>0; off>>=1) {
        if (t < off) { smn[t] = fminf(smn[t], smn[t+off]); smx[t] = fmaxf(smx[t], smx[t+off]); }
        __syncthreads();
    }
    float mn = smn[0], mx = smx[0];
    float outv;
    if (mx == mn) outv = v / (mx == 0.f ? 1.f : mx);
    else          outv = (v - mn) / (mx - mn);
    (axis==0 ? xs : ysn)[row*128 + t] = outv;
}

// ---------------- obj_loc ----------------
__global__ void objloc(const float* __restrict__ xs, const float* __restrict__ ysn,
                       int* __restrict__ box, int N) {
    int i = threadIdx.x;
    if (i >= 2*N*4) return;
    int axis = i / (N*4); int row = i % (N*4);
    const float* s = (axis ? ysn : xs) + (size_t)row*128;
    const int S = 128, minsize = 16;
    int pos[127]; int ncross = 0;
    int prev = sgnf(s[0] - 0.5f);
    for (int k=1; k<S; ++k) {
        int cur = sgnf(s[k] - 0.5f);
        int d = cur - prev; if (d < 0) d = -d;
        if (d == 2) pos[ncross++] = k-1;
        prev = cur;
    }
    float m = -1e30f;
    for (int k=0; k<S; ++k) m = fmaxf(m, s[k]);
    int zmin = 0, zmax = S, bestkey = -2;
    int a = 0;
    for (int j=0; j<=ncross; ++j) {
        int bnd = (j < ncross) ? pos[j] : S;
        float sm = -1e30f;
        for (int k=a; k<bnd; ++k) sm = fmaxf(sm, s[k]);
        int len = bnd - a;
        int key = (sm == m) ? len : -1;
        if (key > bestkey) { bestkey = key; zmin = a; zmax = bnd; }
        a = bnd;
    }
    bool need = (zmax - zmin) <= minsize;
    int pad = minsize - (zmax - zmin);
    int cp = (pad + 1) >> 1;
    bool c1 = need && (zmin > cp) && (S - zmax > pad);
    if (c1) { zmin = zmin - cp + 1; zmax = zmax + cp; }
    bool c2 = need && (zmin < cp);
    if (c2) { zmin = 0; zmax = minsize; }
    bool c3 = need && (S - zmax < cp);
    if (c3) { zmin = S - minsize + 1; zmax = S; }
    if (ncross == 0) { zmin = minsize; zmax = 112; }
    if (axis == 0) { box[row] = zmin; box[32+row] = zmax; }
    else           { box[64+row] = zmin; box[96+row] = zmax; }
}

// ---------------- crop + bilinear resize ----------------
__global__ void crop_resize_k(const float* __restrict__ x, const int* __restrict__ box,
                              float* __restrict__ lin, int N) {
    int idx = blockIdx.x*blockDim.x + threadIdx.x;
    if (idx >= N*4*3*16384) return;
    int xo = idx & 127, yo = (idx>>7)&127;
    int c  = (idx>>14) % 3;
    int r  = idx / 49152;
    int b  = r / 4;
    int cx1 = box[r],    cx2 = box[32+r];
    int cy1 = box[64+r], cy2 = box[96+r];
    float fy = (float)cy1 + (float)(yo * (cy2 - 1 - cy1)) / 127.0f;
    float fx = (float)cx1 + (float)(xo * (cx2 - 1 - cx1)) / 127.0f;
    float wy = fy - floorf(fy);
    float wx = fx - floorf(fx);
    int y0 = min(max((int)floorf(fy), 0), 127); int y1 = min(y0 + 1, 127);
    int x0 = min(max((int)floorf(fx), 0), 127); int x1 = min(x0 + 1, 127);
    const float* img = x + ((size_t)b*3 + c)*16384;
    float v = (1.f-wy)*((1.f-wx)*img[y0*128+x0] + wx*img[y0*128+x1])
            +      wy *((1.f-wx)*img[y1*128+x0] + wx*img[y1*128+x1]);
    lin[idx] = v;
}

// ---------------- local_stream = max over TOPN ----------------
__global__ void local_stream_max(const float* __restrict__ loc, float* __restrict__ out, int N) {
    int idx = threadIdx.x;
    if (idx >= N*20) return;
    int o = idx % 20, b = idx / 20;
    float mv = -1e30f;
    for (int t=0; t<4; ++t) mv = fmaxf(mv, loc[((size_t)(b*4+t))*20 + o]);
    out[idx] = mv;
}

// ---------------- f32 conv stack: K-split everywhere, 8 rounds/block ----------------
static void run_stack_f32(const float* input, int n,
                          const float* c1w, const float* bng, const float* bnb,
                          const float* bnm, const float* bnv,
                          const float* w1, const float* w2, const float* w3, const float* w4,
                          char* O, float** act_out, hipStream_t stream) {
    float* C7  = (float*)(O + 25165824);
    float* W1O = (float*)(O + 0);
    float* P2  = (float*)(O + 16777216);
    float* P3  = (float*)(O + 0);
    float* P4  = (float*)(O + 16777216);

    conv7_bn_tiled<<<4*4*8*n, 256, 0, stream>>>(input, c1w, bng, bnb, bnm, bnv, C7, n);
    conv3_tiled<1,16,16,16,8,512,24,true><<<4*4*8*n, 512, 0, stream>>>(C7, w1, W1O, n, 64, 128, 64,64, 64,64, 0);
    {
        dim3 grid(4*4*8*n, 2);
        conv3_tiled<2,8,8,32,8,256,20,false><<<grid, 256, 0, stream>>>(W1O, w2, P2, n, 128, 256, 64,64, 32,32, 64);
        int L = n*256*1024;
        reduce_relu<<<(L/4+255)/256, 256, 0, stream>>>(P2, P2, L, 2);
    }
    {
        dim3 grid(2*2*16*n, 4);
        conv3_tiled<2,8,8,32,8,256,20,false><<<grid, 256, 0, stream>>>(P2, w3, P3, n, 256, 512, 32,32, 16,16, 64);
        int L = n*512*256;
        reduce_relu<<<(L/4+255)/256, 256, 0, stream>>>(P3, P3, L, 4);
    }
    {
        dim3 grid(1*1*32*n, 8);
        conv3_tiled<2,8,8,32,8,256,20,false><<<grid, 256, 0, stream>>>(P3, w4, P4, n, 512, 1024, 16,16, 8,8, 64);
        int L = n*1024*64;
        reduce_relu<<<(L/4+255)/256, 256, 0, stream>>>(P4, P4, L, 8);
    }
    *act_out = P4;
}

// ---------------- launcher ----------------
extern "C" void kernel_launch(void* const* d_in, const int* in_sizes, int n_in,
                              void* d_out_, int out_size, void* d_ws, size_t ws_size,
                              hipStream_t stream) {
    const float* x    = (const float*)d_in[0];
    const float* c1w  = (const float*)d_in[1];
    const float* bng  = (const float*)d_in[2];
    const float* bnb  = (const float*)d_in[3];
    const float* bnm  = (const float*)d_in[4];
    const float* bnv  = (const float*)d_in[5];
    const float* w1   = (const float*)d_in[6];
    const float* w2   = (const float*)d_in[7];
    const float* w3   = (const float*)d_in[8];
    const float* w4   = (const float*)d_in[9];
    const float* clsw = (const float*)d_in[10];
    const float* clsb = (const float*)d_in[11];
    float* dout = (float*)d_out_;

    float* out_gs = dout + 0;
    float* out_ls = dout + 160;
    float* out_cs = dout + 320;
    float* out_ws = dout + 2621760;
    float* out_hs = dout + 2642240;
    float* out_li = dout + 2662720;

    const size_t NEED = 101662720ull;
    if (ws_size >= NEED) {
        char* wsb = (char*)d_ws;
        ushort* wb1 = (ushort*)(wsb + 0);
        ushort* wb2 = (ushort*)(wsb + 147456);
        ushort* wb3 = (ushort*)(wsb + 737280);
        ushort* wb4 = (ushort*)(wsb + 3096576);
        ushort* R1  = (ushort*)(wsb + 12533760);
        ushort* R2  = (ushort*)(wsb + 29310976);
        ushort* BR  = (ushort*)(wsb + 62865408);
        char*   GO  = wsb + 62865408;
        char* smb = wsb + 100614144;
        float* gmean = (float*)(smb);
        float* gst   = (float*)(smb + 32768);
        float* cam   = (float*)(smb + 33408);
        int*   top   = (int*)  (smb + 74368);
        float* xs    = (float*)(smb + 74496);
        float* ysn   = (float*)(smb + 90880);
        int*   box   = (int*)  (smb + 107264);
        float* lmean = (float*)(smb + 107776);
        float* locf  = (float*)(smb + 238848);
        ushort* wb7  = (ushort*)(smb + 262144);
        float* bns   = (float*)(smb + 282624);
        float* bnb2  = (float*)(smb + 282880);

        wcast<<<288,256,0,stream>>>(w1, wb1, 73728);
        wcast<<<1152,256,0,stream>>>(w2, wb2, 294912);
        wcast<<<4608,256,0,stream>>>(w3, wb3, 1179648);
        wcast<<<18432,256,0,stream>>>(w4, wb4, 4718592);
        wcast7<<<40,256,0,stream>>>(c1w, wb7);
        bnprep<<<1,64,0,stream>>>(bng, bnb, bnm, bnv, bns, bnb2);

        // ---- global branch (f32, feeds discrete decisions) ----
        float* gact = nullptr;
        run_stack_f32(x, 8, c1w, bng, bnb, bnm, bnv, w1, w2, w3, w4, GO, &gact, stream);
        row_mean64<float><<<2048,256,0,stream>>>(gact, gmean, 8192);
        head_sigmoid<<<1,256,0,stream>>>(gmean, clsw, clsb, gst, out_gs, 8);
        cam_kernel<<<40,256,0,stream>>>(gact, clsw, clsb, cam, 8);
        resize_cam<<<10240,256,0,stream>>>(cam, out_cs, 8);
        score_maxred<<<160,256,0,stream>>>(out_cs, out_ws, out_hs, 8);
        topk4<<<1,64,0,stream>>>(gst, top, 8);
        gather_norm<<<64,128,0,stream>>>(out_ws, out_hs, top, xs, ysn, 8);
        objloc<<<1,64,0,stream>>>(xs, ysn, box, 8);
        crop_resize_k<<<6144,256,0,stream>>>(x, box, out_li, 8);

        // ---- local branch (bf16 MFMA throughout) ----
        for (int c = 0; c < 2; ++c) {
            im2row7<<<5120,256,0,stream>>>(out_li, BR, c*16, 65536);
            gemm_conv<<<512,256,0,stream>>>(wb7, BR, R1, 64, 160, 65536, 64, 12, c*16, bns, bnb2);
        }
        for (int c = 0; c < 4; ++c) {
            im2row_k<<<9216,256,0,stream>>>(R1, BR, c*8, 32768, 64, 64, 64, 64, 64, 1, 576);
            gemm_conv<<<512,256,0,stream>>>(wb1, BR, R2, 128, 576, 32768, 128, 12, c*8, nullptr, nullptr);
        }
        for (int c = 0; c < 2; ++c) {
            im2row_k<<<9216,256,0,stream>>>(R2, BR, c*16, 16384, 128, 64, 64, 32, 32, 2, 1152);
            gemm_conv<<<512,256,0,stream>>>(wb2, BR, R1, 256, 1152, 16384, 256, 10, c*16, nullptr, nullptr);
        }
        im2row_k<<<9216,256,0,stream>>>(R1, BR, 0, 8192, 256, 32, 32, 16, 16, 2, 2304);
        gemm_conv<<<512,256,0,stream>>>(wb3, BR, R2, 512, 2304, 8192, 512, 8, 0, nullptr, nullptr);
        im2row_k<<<4608,256,0,stream>>>(R2, BR, 0, 2048, 512, 16, 16, 8, 8, 2, 4608);
        gemm_conv<<<256,256,0,stream>>>(wb4, BR, R1, 1024, 4608, 2048, 1024, 6, 0, nullptr, nullptr);

        row_mean64<ushort><<<8192,256,0,stream>>>(R1, lmean, 32768);
        head_sigmoid<<<3,256,0,stream>>>(lmean, clsw, clsb, locf, (float*)nullptr, 32);
        local_stream_max<<<1,256,0,stream>>>(locf, out_ls, 8);
    } else {
        // -------- f32 fallback --------
        char* O = (char*)d_ws;
        char* smb = O + 33554432;
        float* gmean = (float*)(smb);
        float* gst   = (float*)(smb + 32768);
        float* cam   = (float*)(smb + 33408);
        int*   top   = (int*)  (smb + 74368);
        float* xs    = (float*)(smb + 74496);
        float* ysn   = (float*)(smb + 90880);
        int*   box   = (int*)  (smb + 107264);
        float* lmean = (float*)(smb + 107776);
        float* locf  = (float*)(smb + 238848);

        float* act = nullptr;
        run_stack_f32(x, 8, c1w, bng, bnb, bnm, bnv, w1, w2, w3, w4, O, &act, stream);
        row_mean64<float><<<2048,256,0,stream>>>(act, gmean, 8192);
        head_sigmoid<<<1,256,0,stream>>>(gmean, clsw, clsb, gst, out_gs, 8);
        cam_kernel<<<40,256,0,stream>>>(act, clsw, clsb, cam, 8);
        resize_cam<<<10240,256,0,stream>>>(cam, out_cs, 8);
        score_maxred<<<160,256,0,stream>>>(out_cs, out_ws, out_hs, 8);
        topk4<<<1,64,0,stream>>>(gst, top, 8);
        gather_norm<<<64,128,0,stream>>>(out_ws, out_hs, top, xs, ysn, 8);
        objloc<<<1,64,0,stream>>>(xs, ysn, box, 8);
        crop_resize_k<<<6144,256,0,stream>>>(x, box, out_li, 8);

        for (int c = 0; c < 4; ++c) {
            const float* lin_c = out_li + (size_t)c*8*3*16384;
            run_stack_f32(lin_c, 8, c1w, bng, bnb, bnm, bnv, w1, w2, w3, w4, O, &act, stream);
            row_mean64<float><<<2048,256,0,stream>>>(act, lmean + c*8192, 8192);
        }
        head_sigmoid<<<3,256,0,stream>>>(lmean, clsw, clsb, locf, (float*)nullptr, 32);
        local_stream_max<<<1,256,0,stream>>>(locf, out_ls, 8);
    }
}

// Round 12
// 1437.339 us; speedup vs baseline: 1.1517x; 1.0112x over previous
//
#include <hip/hip_runtime.h>
#include <hip/hip_bf16.h>

// ---------------- helpers ----------------
__device__ __forceinline__ int sgnf(float v){ return (v>0.f)-(v<0.f); }
__device__ __forceinline__ ushort f2b(float f){ __hip_bfloat16 h = __float2bfloat16(f); return __builtin_bit_cast(ushort, h); }
__device__ __forceinline__ float  b2f(ushort u){ __hip_bfloat16 h = __builtin_bit_cast(__hip_bfloat16, u); return __bfloat162float(h); }
__device__ __forceinline__ float  tof(float v){ return v; }
__device__ __forceinline__ float  tof(ushort v){ return b2f(v); }

typedef short  s8v  __attribute__((ext_vector_type(8)));
typedef ushort us8  __attribute__((ext_vector_type(8)));
typedef float  f4v  __attribute__((ext_vector_type(4)));

#if __has_builtin(__builtin_amdgcn_global_load_lds)
#define USE_GLL 1
typedef __attribute__((address_space(1))) void gvoid;
typedef __attribute__((address_space(3))) void lvoid;
#else
#define USE_GLL 0
#endif

// =====================================================================
// f32 tiled 3x3 conv (verified 2x4 tile).
// RELU=true: full conv + relu. RELU=false: K-split partial (raw, slab y).
// =====================================================================
template<int STRIDE, int TH, int TW, int CO_T, int CI_T, int NT, int P, bool RELU>
__global__ __launch_bounds__(NT) void conv3_tiled(
    const float* __restrict__ in, const float* __restrict__ w, float* __restrict__ out,
    int N, int Ci, int Co, int Hi, int Wi, int Ho, int Wo, int ciLen)
{
    constexpr int NSP   = (TH/2)*(TW/4);
    constexpr int IT_H  = (TH-1)*STRIDE + 3;
    constexpr int IT_W  = (TW-1)*STRIDE + 3;
    constexpr int IN_ELEMS = CI_T*IT_H*IT_W;
    constexpr int W_ELEMS  = CI_T*CO_T*9;
    static_assert(NSP*CO_T == NT, "thread count mismatch");
    static_assert(IT_W <= P, "pitch too small");

    __shared__ __align__(16) float s_in[CI_T*IT_H*P];
    __shared__ __align__(16) float s_w[CI_T*CO_T*12];

    int bx = blockIdx.x;
    const int spxn = Wo/TW, spyn = Ho/TH, cog = Co/CO_T;
    const int sxb = bx % spxn; bx /= spxn;
    const int syb = bx % spyn; bx /= spyn;
    const int cg  = bx % cog;  const int n = bx / cog;
    const int tx0 = sxb*TW, ty0 = syb*TH, co0 = cg*CO_T;

    const int ciStart = RELU ? 0 : blockIdx.y * ciLen;
    const int ciEnd   = RELU ? Ci : ciStart + ciLen;
    if (!RELU) out += (size_t)blockIdx.y * N * Co * Ho * Wo;

    const int tid = threadIdx.x;
    const int sp  = tid % NSP;
    const int co  = tid / NSP;
    const int sy  = (sp / (TW/4)) * 2;
    const int sx  = (sp % (TW/4)) * 4;

    const int y_in0 = ty0*STRIDE - 1, x_in0 = tx0*STRIDE - 1;
    const float* in_n = in + (size_t)n*Ci*Hi*Wi;

    float acc[2][4] = {{0.f,0.f,0.f,0.f},{0.f,0.f,0.f,0.f}};

    for (int ci0 = ciStart; ci0 < ciEnd; ci0 += CI_T) {
        for (int idx = tid; idx < IN_ELEMS; idx += NT) {
            int ci  = idx / (IT_H*IT_W);
            int rem = idx - ci*(IT_H*IT_W);
            int iy  = rem / IT_W;
            int ix  = rem - iy*IT_W;
            int gy = y_in0 + iy, gx = x_in0 + ix;
            float v = 0.f;
            if ((unsigned)gy < (unsigned)Hi && (unsigned)gx < (unsigned)Wi)
                v = in_n[(size_t)(ci0+ci)*Hi*Wi + gy*Wi + gx];
            s_in[ci*(IT_H*P) + iy*P + ix] = v;
        }
        for (int idx = tid; idx < W_ELEMS; idx += NT) {
            int ci  = idx / (CO_T*9);
            int rem = idx - ci*(CO_T*9);
            int c   = rem / 9, k = rem - c*9;
            s_w[(ci*CO_T + c)*12 + k] = w[((size_t)(co0+c)*Ci + (ci0+ci))*9 + k];
        }
        __syncthreads();

        #pragma unroll
        for (int ci = 0; ci < CI_T; ++ci) {
            const float* wp = &s_w[(ci*CO_T + co)*12];
            float4 wa = *(const float4*)wp;
            float4 wb = *(const float4*)(wp+4);
            float w8  = wp[8];
            float wr[9] = {wa.x,wa.y,wa.z,wa.w, wb.x,wb.y,wb.z,wb.w, w8};
            const float* ip = &s_in[ci*(IT_H*P)];

            if constexpr (STRIDE == 1) {
                #pragma unroll
                for (int pr = 0; pr < 4; ++pr) {
                    const float* row = ip + (sy+pr)*P + sx;
                    float4 a = *(const float4*)row;
                    float2 b = *(const float2*)(row+4);
                    float e[6] = {a.x,a.y,a.z,a.w,b.x,b.y};
                    #pragma unroll
                    for (int ky = 0; ky < 3; ++ky) {
                        int ry = pr - ky;
                        if (ry == 0 || ry == 1) {
                            #pragma unroll
                            for (int kx = 0; kx < 3; ++kx)
                                #pragma unroll
                                for (int rx = 0; rx < 4; ++rx)
                                    acc[ry][rx] += e[rx+kx] * wr[ky*3+kx];
                        }
                    }
                }
            } else {
                #pragma unroll
                for (int pr = 0; pr < 5; ++pr) {
                    const float* row = ip + (2*sy+pr)*P + 2*sx;
                    float4 a = *(const float4*)row;
                    float4 b = *(const float4*)(row+4);
                    float c8 = row[8];
                    float e[9] = {a.x,a.y,a.z,a.w,b.x,b.y,b.z,b.w,c8};
                    #pragma unroll
                    for (int ky = 0; ky < 3; ++ky) {
                        int ry2 = pr - ky;
                        if (ry2 == 0 || ry2 == 2) {
                            int ry = ry2 >> 1;
                            #pragma unroll
                            for (int kx = 0; kx < 3; ++kx)
                                #pragma unroll
                                for (int rx = 0; rx < 4; ++rx)
                                    acc[ry][rx] += e[2*rx+kx] * wr[ky*3+kx];
                        }
                    }
                }
            }
        }
        __syncthreads();
    }

    float* op = out + ((size_t)n*Co + co0 + co)*Ho*Wo + (size_t)(ty0+sy)*Wo + (tx0+sx);
    #pragma unroll
    for (int ry=0; ry<2; ++ry) {
        float4 v;
        if constexpr (RELU) {
            v.x = fmaxf(acc[ry][0], 0.f); v.y = fmaxf(acc[ry][1], 0.f);
            v.z = fmaxf(acc[ry][2], 0.f); v.w = fmaxf(acc[ry][3], 0.f);
        } else {
            v.x = acc[ry][0]; v.y = acc[ry][1]; v.z = acc[ry][2]; v.w = acc[ry][3];
        }
        *(float4*)(op + (size_t)ry*Wo) = v;
    }
}

// ---------------- sum K partial slabs + relu (out may alias slab 0) ----------------
__global__ void reduce_relu(const float* __restrict__ part, float* __restrict__ out,
                            int L, int KS) {
    int i = (blockIdx.x*blockDim.x + threadIdx.x) * 4;
    if (i >= L) return;
    float4 s = *(const float4*)&part[i];
    for (int k = 1; k < KS; ++k) {
        float4 p = *(const float4*)&part[(size_t)k*L + i];
        s.x += p.x; s.y += p.y; s.z += p.z; s.w += p.w;
    }
    s.x = fmaxf(s.x, 0.f); s.y = fmaxf(s.y, 0.f);
    s.z = fmaxf(s.z, 0.f); s.w = fmaxf(s.w, 0.f);
    *(float4*)&out[i] = s;
}

// =====================================================================
// 7x7 s2 p3 conv + BN, f32 (global branch)
// =====================================================================
__global__ __launch_bounds__(256) void conv7_bn_tiled(
    const float* __restrict__ x, const float* __restrict__ w,
    const float* __restrict__ gamma, const float* __restrict__ beta,
    const float* __restrict__ mean, const float* __restrict__ var,
    float* __restrict__ out, int N)
{
    constexpr int IT = 37;
    constexpr int P  = 38;
    constexpr int NT = 256;
    constexpr int IN_ELEMS = 3*IT*IT;
    constexpr int W_ELEMS  = 8*3*49;

    __shared__ __align__(16) float s_in[3*IT*P];
    __shared__ __align__(16) float s_w[8*3*7*8];

    int bx = blockIdx.x;
    const int sxb = bx % 4; bx /= 4;
    const int syb = bx % 4; bx /= 4;
    const int cg  = bx % 8; const int n = bx / 8;
    const int tx0 = sxb*16, ty0 = syb*16, co0 = cg*8;

    const int tid = threadIdx.x;
    const int sp  = tid % 32;
    const int co  = tid / 32;
    const int sy  = (sp / 4) * 2;
    const int sx  = (sp % 4) * 4;

    const int y_in0 = ty0*2 - 3, x_in0 = tx0*2 - 3;
    const float* x_n = x + (size_t)n*3*16384;

    for (int idx = tid; idx < IN_ELEMS; idx += NT) {
        int ci  = idx / (IT*IT);
        int rem = idx - ci*(IT*IT);
        int iy  = rem / IT;
        int ix  = rem - iy*IT;
        int gy = y_in0 + iy, gx = x_in0 + ix;
        float v = 0.f;
        if ((unsigned)gy < 128u && (unsigned)gx < 128u)
            v = x_n[(size_t)ci*16384 + gy*128 + gx];
        s_in[ci*(IT*P) + iy*P + ix] = v;
    }
    for (int idx = tid; idx < W_ELEMS; idx += NT) {
        int c   = idx / 147;
        int rem = idx - c*147;
        int ci  = rem / 49;
        int rem2= rem - ci*49;
        int ky  = rem2 / 7, kx = rem2 - ky*7;
        s_w[((c*3 + ci)*7 + ky)*8 + kx] = w[(size_t)(co0+c)*147 + ci*49 + ky*7 + kx];
    }
    __syncthreads();

    float acc[2][4] = {{0.f,0.f,0.f,0.f},{0.f,0.f,0.f,0.f}};
    const int c0 = 2*sx;
    #pragma unroll 1
    for (int ci = 0; ci < 3; ++ci) {
        const float* ip = &s_in[ci*(IT*P)];
        #pragma unroll
        for (int pr = 0; pr < 9; ++pr) {
            const float* row = ip + (2*sy+pr)*P + c0;
            float2 q0 = *(const float2*)(row+0);
            float2 q1 = *(const float2*)(row+2);
            float2 q2 = *(const float2*)(row+4);
            float2 q3 = *(const float2*)(row+6);
            float2 q4 = *(const float2*)(row+8);
            float2 q5 = *(const float2*)(row+10);
            float  e12 = row[12];
            float e[13] = {q0.x,q0.y,q1.x,q1.y,q2.x,q2.y,q3.x,q3.y,q4.x,q4.y,q5.x,q5.y,e12};
            #pragma unroll
            for (int ry = 0; ry < 2; ++ry) {
                int ky = pr - 2*ry;
                if (ky >= 0 && ky < 7) {
                    const float* wrow = &s_w[((co*3 + ci)*7 + ky)*8];
                    float4 wa = *(const float4*)wrow;
                    float2 wbv = *(const float2*)(wrow+4);
                    float w6 = wrow[6];
                    float wk[7] = {wa.x,wa.y,wa.z,wa.w,wbv.x,wbv.y,w6};
                    #pragma unroll
                    for (int kx = 0; kx < 7; ++kx)
                        #pragma unroll
                        for (int rx = 0; rx < 4; ++rx)
                            acc[ry][rx] += e[2*rx+kx] * wk[kx];
                }
            }
        }
    }

    const int coo = co0 + co;
    float inv = gamma[coo] / sqrtf(var[coo] + 1e-5f);
    float mu = mean[coo], bb = beta[coo];
    float* op = out + ((size_t)n*64 + coo)*4096 + (size_t)(ty0+sy)*64 + (tx0+sx);
    #pragma unroll
    for (int ry=0; ry<2; ++ry) {
        float4 v;
        v.x = (acc[ry][0]-mu)*inv + bb; v.y = (acc[ry][1]-mu)*inv + bb;
        v.z = (acc[ry][2]-mu)*inv + bb; v.w = (acc[ry][3]-mu)*inv + bb;
        *(float4*)(op + (size_t)ry*64) = v;
    }
}

// ---------------- fused weight prep: all casts + conv1 pad + BN affine ----------------
__global__ void wprep(const float* __restrict__ w1, const float* __restrict__ w2,
                      const float* __restrict__ w3, const float* __restrict__ w4,
                      const float* __restrict__ c1w,
                      const float* __restrict__ g, const float* __restrict__ be,
                      const float* __restrict__ mu, const float* __restrict__ va,
                      ushort* __restrict__ wb1, ushort* __restrict__ wb2,
                      ushort* __restrict__ wb3, ushort* __restrict__ wb4,
                      ushort* __restrict__ wb7,
                      float* __restrict__ bns, float* __restrict__ bnb2) {
    int i = blockIdx.x*blockDim.x + threadIdx.x;
    // segments: w4 4718592 | w3 1179648 | w2 294912 | w1 73728 | wb7 10240 | bn 64
    if (i < 4718592) { wb4[i] = f2b(w4[i]); return; }
    i -= 4718592;
    if (i < 1179648) { wb3[i] = f2b(w3[i]); return; }
    i -= 1179648;
    if (i < 294912)  { wb2[i] = f2b(w2[i]); return; }
    i -= 294912;
    if (i < 73728)   { wb1[i] = f2b(w1[i]); return; }
    i -= 73728;
    if (i < 10240) {
        int co = i / 160, k = i - co*160;
        wb7[i] = (k < 147) ? f2b(c1w[co*147 + k]) : (ushort)0;
        return;
    }
    i -= 10240;
    if (i < 64) {
        float sv = g[i] / sqrtf(va[i] + 1e-5f);
        bns[i] = sv;
        bnb2[i] = be[i] - mu[i]*sv;
    }
}

// ---------------- im2row (bf16 NCHW -> Brow[p][k]) for 3x3 ----------------
__global__ void im2row_k(const ushort* __restrict__ in, ushort* __restrict__ Brow,
                         int n0, int NN, int Ci, int Hi, int Wi, int Ho, int Wo,
                         int stride, int K) {
    int idx = blockIdx.x*blockDim.x + threadIdx.x;
    int K8 = K >> 3;
    if (idx >= NN * K8) return;
    int ks = idx % K8;
    int p  = idx / K8;
    int xo = p % Wo; int t = p / Wo; int yo = t % Ho; int nl = t / Ho;
    const ushort* ip = in + (size_t)(n0 + nl)*Ci*Hi*Wi;
    int y0 = yo*stride - 1, x0 = xo*stride - 1;
    us8 v;
    #pragma unroll
    for (int j = 0; j < 8; ++j) {
        int k = ks*8 + j;
        int ci = k / 9, tt = k - ci*9;
        int ky = tt / 3, kx = tt - ky*3;
        int yi = y0 + ky, xi = x0 + kx;
        ushort val = 0;
        if ((unsigned)yi < (unsigned)Hi && (unsigned)xi < (unsigned)Wi)
            val = ip[(size_t)ci*Hi*Wi + yi*Wi + xi];
        v[j] = val;
    }
    *(us8*)&Brow[(size_t)p*K + ks*8] = v;
}

// ---------------- im2row for conv1 7x7 s2 p3: f32 input -> bf16 rows K=160 ----------------
__global__ void im2row7(const float* __restrict__ in, ushort* __restrict__ Brow,
                        int n0, int NN) {
    int idx = blockIdx.x*blockDim.x + threadIdx.x;
    if (idx >= NN * 20) return;
    int ks = idx % 20;
    int p  = idx / 20;
    int xo = p & 63; int t = p >> 6; int yo = t & 63; int nl = t >> 6;
    const float* ip = in + (size_t)(n0 + nl)*3*16384;
    int y0 = yo*2 - 3, x0 = xo*2 - 3;
    us8 v;
    #pragma unroll
    for (int j = 0; j < 8; ++j) {
        int k = ks*8 + j;
        ushort val = 0;
        if (k < 147) {
            int ci = k / 49, tt = k - ci*49;
            int ky = tt / 7, kx = tt - ky*7;
            int yi = y0 + ky, xi = x0 + kx;
            if ((unsigned)yi < 128u && (unsigned)xi < 128u)
                val = f2b(ip[(size_t)ci*16384 + yi*128 + xi]);
        }
        v[j] = val;
    }
    *(us8*)&Brow[(size_t)p*160 + ks*8] = v;
}

// ---------------- bf16 MFMA GEMM; epilogue relu (sc==null) or BN affine ----------------
__global__ __launch_bounds__(256) void gemm_conv(
    const ushort* __restrict__ A, const ushort* __restrict__ B,
    ushort* __restrict__ out,
    int M, int K, int NN, int Co, int hwShift, int n0,
    const float* __restrict__ sc, const float* __restrict__ bi)
{
    __shared__ __align__(16) ushort sA[64*32];
    __shared__ __align__(16) ushort sB[128*32];

    int bx = blockIdx.x;
    int mtiles = M >> 6;
    int mt = bx % mtiles;
    int nt = bx / mtiles;
    int co0 = mt << 6, p0 = nt << 7;
    int tid = threadIdx.x, lane = tid & 63, wave = tid >> 6;
    int wm = wave & 1, wn = wave >> 1;

    f4v acc[2][4];
    #pragma unroll
    for (int i=0;i<2;++i)
        #pragma unroll
        for (int j=0;j<4;++j)
            #pragma unroll
            for (int r=0;r<4;++r) acc[i][j][r] = 0.f;

    const int g  = lane >> 4;
    const int li = lane & 15;

    for (int k0 = 0; k0 < K; k0 += 32) {
#if USE_GLL
        {
            int r = tid >> 2;
            int s = (lane & 3) ^ ((r >> 1) & 3);
            const ushort* gp = &A[(size_t)(co0 + r)*K + k0 + s*8];
            __builtin_amdgcn_global_load_lds((gvoid*)gp, (lvoid*)&sA[wave*512], 16, 0, 0);
        }
        #pragma unroll
        for (int h = 0; h < 2; ++h) {
            int slot = tid + h*256;
            int r = slot >> 2;
            int s = (lane & 3) ^ ((r >> 1) & 3);
            const ushort* gp = &B[(size_t)(p0 + r)*K + k0 + s*8];
            __builtin_amdgcn_global_load_lds((gvoid*)gp, (lvoid*)&sB[(h*4 + wave)*512], 16, 0, 0);
        }
#else
        {
            int r = tid >> 2, s = tid & 3;
            int sp = s ^ ((r >> 1) & 3);
            us8 val = *(const us8*)&A[(size_t)(co0 + r)*K + k0 + s*8];
            *(us8*)&sA[r*32 + sp*8] = val;
        }
        #pragma unroll
        for (int h = 0; h < 2; ++h) {
            int slot = tid + h*256;
            int r = slot >> 2, s = slot & 3;
            int sp = s ^ ((r >> 1) & 3);
            us8 val = *(const us8*)&B[(size_t)(p0 + r)*K + k0 + s*8];
            *(us8*)&sB[r*32 + sp*8] = val;
        }
#endif
        __syncthreads();

        s8v a0, a1, b0, b1, b2, b3;
        {
            int r = wm*32 + li;
            a0 = *(const s8v*)&sA[r*32 + ((g ^ ((r>>1)&3)))*8];
            int r2 = r + 16;
            a1 = *(const s8v*)&sA[r2*32 + ((g ^ ((r2>>1)&3)))*8];
        }
        {
            int r = wn*64 + li;
            b0 = *(const s8v*)&sB[r*32 + ((g ^ ((r>>1)&3)))*8];
            int r1 = r + 16;
            b1 = *(const s8v*)&sB[r1*32 + ((g ^ ((r1>>1)&3)))*8];
            int r2 = r + 32;
            b2 = *(const s8v*)&sB[r2*32 + ((g ^ ((r2>>1)&3)))*8];
            int r3 = r + 48;
            b3 = *(const s8v*)&sB[r3*32 + ((g ^ ((r3>>1)&3)))*8];
        }
        acc[0][0] = __builtin_amdgcn_mfma_f32_16x16x32_bf16(a0, b0, acc[0][0], 0, 0, 0);
        acc[0][1] = __builtin_amdgcn_mfma_f32_16x16x32_bf16(a0, b1, acc[0][1], 0, 0, 0);
        acc[0][2] = __builtin_amdgcn_mfma_f32_16x16x32_bf16(a0, b2, acc[0][2], 0, 0, 0);
        acc[0][3] = __builtin_amdgcn_mfma_f32_16x16x32_bf16(a0, b3, acc[0][3], 0, 0, 0);
        acc[1][0] = __builtin_amdgcn_mfma_f32_16x16x32_bf16(a1, b0, acc[1][0], 0, 0, 0);
        acc[1][1] = __builtin_amdgcn_mfma_f32_16x16x32_bf16(a1, b1, acc[1][1], 0, 0, 0);
        acc[1][2] = __builtin_amdgcn_mfma_f32_16x16x32_bf16(a1, b2, acc[1][2], 0, 0, 0);
        acc[1][3] = __builtin_amdgcn_mfma_f32_16x16x32_bf16(a1, b3, acc[1][3], 0, 0, 0);
        __syncthreads();
    }

    int hwMask = (1 << hwShift) - 1;
    #pragma unroll
    for (int i = 0; i < 2; ++i) {
        #pragma unroll
        for (int j = 0; j < 4; ++j) {
            #pragma unroll
            for (int r = 0; r < 4; ++r) {
                int co = co0 + wm*32 + i*16 + g*4 + r;
                int p  = p0 + wn*64 + j*16 + li;
                int nimg = p >> hwShift, sphw = p & hwMask;
                float v = acc[i][j][r];
                if (sc) v = v * sc[co] + bi[co];
                else    v = fmaxf(v, 0.f);
                out[(((size_t)(n0 + nimg)*Co + co) << hwShift) + sphw] = f2b(v);
            }
        }
    }
}

// ---------------- per-row (64-elem) mean via wave reduce ----------------
template<typename T>
__global__ void row_mean64(const T* __restrict__ in, float* __restrict__ out, int rows) {
    int w = (blockIdx.x*blockDim.x + threadIdx.x) >> 6;
    int lane = threadIdx.x & 63;
    if (w >= rows) return;
    float v = tof(in[(size_t)w*64 + lane]);
    #pragma unroll
    for (int off = 32; off > 0; off >>= 1) v += __shfl_down(v, off, 64);
    if (lane == 0) out[w] = v * (1.f/64.f);
}

// ---------------- classifier head ----------------
__global__ void head_sigmoid(const float* __restrict__ m, const float* __restrict__ cw,
                             const float* __restrict__ cb, float* __restrict__ out0,
                             float* __restrict__ out1, int Nrows) {
    int idx = blockIdx.x*blockDim.x + threadIdx.x;
    if (idx >= Nrows*20) return;
    int o = idx % 20, n = idx / 20;
    const float* mp = m + (size_t)n*1024;
    const float* wp = cw + (size_t)o*1024;
    float s = cb[o];
    for (int c=0;c<1024;++c) s += mp[c]*wp[c];
    float v = 1.f/(1.f+expf(-s));
    out0[idx] = v;
    if (out1) out1[idx] = v;
}

// ---------------- cam ----------------
__global__ void cam_kernel(const float* __restrict__ act, const float* __restrict__ cw,
                           const float* __restrict__ cb, float* __restrict__ cam, int N) {
    int idx = blockIdx.x*blockDim.x + threadIdx.x;
    if (idx >= N*20*64) return;
    int p = idx & 63; int o = (idx>>6) % 20; int n = idx / 1280;
    const float* a = act + (size_t)n*1024*64 + p;
    const float* wp = cw + (size_t)o*1024;
    float s = cb[o];
    for (int c=0;c<1024;++c) s += a[c*64]*wp[c];
    cam[idx] = 1.f/(1.f+expf(-s));
}

// ---------------- bilinear resize cam ----------------
__global__ void resize_cam(const float* __restrict__ cam, float* __restrict__ cs, int N) {
    int idx = blockIdx.x*blockDim.x + threadIdx.x;
    if (idx >= N*20*16384) return;
    int xo = idx & 127, yo = (idx>>7)&127;
    int bo = idx >> 14;
    float fy = (float)yo * (7.0f/127.0f);
    float fx = (float)xo * (7.0f/127.0f);
    int y0 = (int)floorf(fy); float wy = fy - (float)y0;
    int x0 = (int)floorf(fx); float wx = fx - (float)x0;
    if (y0 > 7) y0 = 7; if (y0 < 0) y0 = 0; int y1 = min(y0+1, 7);
    if (x0 > 7) x0 = 7; if (x0 < 0) x0 = 0; int x1 = min(x0+1, 7);
    const float* c = cam + (size_t)bo*64;
    float v = (1.f-wy)*((1.f-wx)*c[y0*8+x0] + wx*c[y0*8+x1])
            +      wy *((1.f-wx)*c[y1*8+x0] + wx*c[y1*8+x1]);
    cs[idx] = v;
}

// ---------------- wscore / hscore max reductions ----------------
__global__ void score_maxred(const float* __restrict__ cs, float* __restrict__ wsc,
                             float* __restrict__ hsc, int N) {
    int idx = blockIdx.x*blockDim.x + threadIdx.x;
    int total = N*20*128;
    if (idx >= 2*total) return;
    if (idx < total) {
        int wcol = idx % 128; int bo = idx / 128;
        const float* p = cs + (size_t)bo*16384 + wcol;
        float mv = -1e30f;
        for (int h=0; h<128; ++h) mv = fmaxf(mv, p[h*128]);
        wsc[idx] = mv;
    } else {
        int i = idx - total;
        int hrow = i % 128; int bo = i / 128;
        const float* p = cs + (size_t)bo*16384 + hrow*128;
        float mv = -1e30f;
        for (int w_=0; w_<128; ++w_) mv = fmaxf(mv, p[w_]);
        hsc[i] = mv;
    }
}

// ---------------- stable top-4 of 20 per batch ----------------
__global__ void topk4(const float* __restrict__ gs, int* __restrict__ top, int N) {
    int n = threadIdx.x;
    if (n >= N) return;
    const float* g = gs + n*20;
    bool used[20];
    for (int i=0;i<20;++i) used[i]=false;
    for (int t=0;t<4;++t) {
        int bi = -1; float bv = -1e30f;
        for (int i=0;i<20;++i) {
            if (!used[i] && g[i] > bv) { bv = g[i]; bi = i; }
        }
        used[bi] = true;
        top[n*4+t] = bi;
    }
}

// ---------------- gather top rows + norm01 ----------------
__global__ void gather_norm(const float* __restrict__ wsc, const float* __restrict__ hsc,
                            const int* __restrict__ top, float* __restrict__ xs,
                            float* __restrict__ ysn, int N) {
    int r = blockIdx.x;
    int axis = r / (N*4); int row = r % (N*4);
    int b = row / 4;
    int cls = top[row];
    const float* src = (axis==0 ? wsc : hsc) + ((size_t)b*20 + cls)*128;
    int t = threadIdx.x;
    float v = src[t];
    __shared__ float smn[128], smx[128];
    smn[t] = v; smx[t] = v;
    __syncthreads();
    for (int off=64; off>0; off>>=1) {
        if (t < off) { smn[t] = fminf(smn[t], smn[t+off]); smx[t] = fmaxf(smx[t], smx[t+off]); }
        __syncthreads();
    }
    float mn = smn[0], mx = smx[0];
    float outv;
    if (mx == mn) outv = v / (mx == 0.f ? 1.f : mx);
    else          outv = (v - mn) / (mx - mn);
    (axis==0 ? xs : ysn)[row*128 + t] = outv;
}

// ---------------- obj_loc ----------------
__global__ void objloc(const float* __restrict__ xs, const float* __restrict__ ysn,
                       int* __restrict__ box, int N) {
    int i = threadIdx.x;
    if (i >= 2*N*4) return;
    int axis = i / (N*4); int row = i % (N*4);
    const float* s = (axis ? ysn : xs) + (size_t)row*128;
    const int S = 128, minsize = 16;
    int pos[127]; int ncross = 0;
    int prev = sgnf(s[0] - 0.5f);
    for (int k=1; k<S; ++k) {
        int cur = sgnf(s[k] - 0.5f);
        int d = cur - prev; if (d < 0) d = -d;
        if (d == 2) pos[ncross++] = k-1;
        prev = cur;
    }
    float m = -1e30f;
    for (int k=0; k<S; ++k) m = fmaxf(m, s[k]);
    int zmin = 0, zmax = S, bestkey = -2;
    int a = 0;
    for (int j=0; j<=ncross; ++j) {
        int bnd = (j < ncross) ? pos[j] : S;
        float sm = -1e30f;
        for (int k=a; k<bnd; ++k) sm = fmaxf(sm, s[k]);
        int len = bnd - a;
        int key = (sm == m) ? len : -1;
        if (key > bestkey) { bestkey = key; zmin = a; zmax = bnd; }
        a = bnd;
    }
    bool need = (zmax - zmin) <= minsize;
    int pad = minsize - (zmax - zmin);
    int cp = (pad + 1) >> 1;
    bool c1 = need && (zmin > cp) && (S - zmax > pad);
    if (c1) { zmin = zmin - cp + 1; zmax = zmax + cp; }
    bool c2 = need && (zmin < cp);
    if (c2) { zmin = 0; zmax = minsize; }
    bool c3 = need && (S - zmax < cp);
    if (c3) { zmin = S - minsize + 1; zmax = S; }
    if (ncross == 0) { zmin = minsize; zmax = 112; }
    if (axis == 0) { box[row] = zmin; box[32+row] = zmax; }
    else           { box[64+row] = zmin; box[96+row] = zmax; }
}

// ---------------- crop + bilinear resize ----------------
__global__ void crop_resize_k(const float* __restrict__ x, const int* __restrict__ box,
                              float* __restrict__ lin, int N) {
    int idx = blockIdx.x*blockDim.x + threadIdx.x;
    if (idx >= N*4*3*16384) return;
    int xo = idx & 127, yo = (idx>>7)&127;
    int c  = (idx>>14) % 3;
    int r  = idx / 49152;
    int b  = r / 4;
    int cx1 = box[r],    cx2 = box[32+r];
    int cy1 = box[64+r], cy2 = box[96+r];
    float fy = (float)cy1 + (float)(yo * (cy2 - 1 - cy1)) / 127.0f;
    float fx = (float)cx1 + (float)(xo * (cx2 - 1 - cx1)) / 127.0f;
    float wy = fy - floorf(fy);
    float wx = fx - floorf(fx);
    int y0 = min(max((int)floorf(fy), 0), 127); int y1 = min(y0 + 1, 127);
    int x0 = min(max((int)floorf(fx), 0), 127); int x1 = min(x0 + 1, 127);
    const float* img = x + ((size_t)b*3 + c)*16384;
    float v = (1.f-wy)*((1.f-wx)*img[y0*128+x0] + wx*img[y0*128+x1])
            +      wy *((1.f-wx)*img[y1*128+x0] + wx*img[y1*128+x1]);
    lin[idx] = v;
}

// ---------------- local_stream = max over TOPN ----------------
__global__ void local_stream_max(const float* __restrict__ loc, float* __restrict__ out, int N) {
    int idx = threadIdx.x;
    if (idx >= N*20) return;
    int o = idx % 20, b = idx / 20;
    float mv = -1e30f;
    for (int t=0; t<4; ++t) mv = fmaxf(mv, loc[((size_t)(b*4+t))*20 + o]);
    out[idx] = mv;
}

// ---------------- f32 conv stack: K-split, CI_T=4 (smaller LDS, more blocks/CU) ----------------
static void run_stack_f32(const float* input, int n,
                          const float* c1w, const float* bng, const float* bnb,
                          const float* bnm, const float* bnv,
                          const float* w1, const float* w2, const float* w3, const float* w4,
                          char* O, float** act_out, hipStream_t stream) {
    float* C7  = (float*)(O + 25165824);
    float* W1O = (float*)(O + 0);
    float* P2  = (float*)(O + 16777216);
    float* P3  = (float*)(O + 0);
    float* P4  = (float*)(O + 16777216);

    conv7_bn_tiled<<<4*4*8*n, 256, 0, stream>>>(input, c1w, bng, bnb, bnm, bnv, C7, n);
    conv3_tiled<1,16,16,16,4,512,24,true><<<4*4*8*n, 512, 0, stream>>>(C7, w1, W1O, n, 64, 128, 64,64, 64,64, 0);
    {
        dim3 grid(4*4*8*n, 2);
        conv3_tiled<2,8,8,32,4,256,20,false><<<grid, 256, 0, stream>>>(W1O, w2, P2, n, 128, 256, 64,64, 32,32, 64);
        int L = n*256*1024;
        reduce_relu<<<(L/4+255)/256, 256, 0, stream>>>(P2, P2, L, 2);
    }
    {
        dim3 grid(2*2*16*n, 4);
        conv3_tiled<2,8,8,32,4,256,20,false><<<grid, 256, 0, stream>>>(P2, w3, P3, n, 256, 512, 32,32, 16,16, 64);
        int L = n*512*256;
        reduce_relu<<<(L/4+255)/256, 256, 0, stream>>>(P3, P3, L, 4);
    }
    {
        dim3 grid(1*1*32*n, 8);
        conv3_tiled<2,8,8,32,4,256,20,false><<<grid, 256, 0, stream>>>(P3, w4, P4, n, 512, 1024, 16,16, 8,8, 64);
        int L = n*1024*64;
        reduce_relu<<<(L/4+255)/256, 256, 0, stream>>>(P4, P4, L, 8);
    }
    *act_out = P4;
}

// ---------------- launcher ----------------
extern "C" void kernel_launch(void* const* d_in, const int* in_sizes, int n_in,
                              void* d_out_, int out_size, void* d_ws, size_t ws_size,
                              hipStream_t stream) {
    const float* x    = (const float*)d_in[0];
    const float* c1w  = (const float*)d_in[1];
    const float* bng  = (const float*)d_in[2];
    const float* bnb  = (const float*)d_in[3];
    const float* bnm  = (const float*)d_in[4];
    const float* bnv  = (const float*)d_in[5];
    const float* w1   = (const float*)d_in[6];
    const float* w2   = (const float*)d_in[7];
    const float* w3   = (const float*)d_in[8];
    const float* w4   = (const float*)d_in[9];
    const float* clsw = (const float*)d_in[10];
    const float* clsb = (const float*)d_in[11];
    float* dout = (float*)d_out_;

    float* out_gs = dout + 0;
    float* out_ls = dout + 160;
    float* out_cs = dout + 320;
    float* out_ws = dout + 2621760;
    float* out_hs = dout + 2642240;
    float* out_li = dout + 2662720;

    const size_t NEED = 101662720ull;
    if (ws_size >= NEED) {
        char* wsb = (char*)d_ws;
        ushort* wb1 = (ushort*)(wsb + 0);
        ushort* wb2 = (ushort*)(wsb + 147456);
        ushort* wb3 = (ushort*)(wsb + 737280);
        ushort* wb4 = (ushort*)(wsb + 3096576);
        ushort* R1  = (ushort*)(wsb + 12533760);
        ushort* R2  = (ushort*)(wsb + 29310976);
        ushort* BR  = (ushort*)(wsb + 62865408);
        char*   GO  = wsb + 62865408;
        char* smb = wsb + 100614144;
        float* gmean = (float*)(smb);
        float* gst   = (float*)(smb + 32768);
        float* cam   = (float*)(smb + 33408);
        int*   top   = (int*)  (smb + 74368);
        float* xs    = (float*)(smb + 74496);
        float* ysn   = (float*)(smb + 90880);
        int*   box   = (int*)  (smb + 107264);
        float* lmean = (float*)(smb + 107776);
        float* locf  = (float*)(smb + 238848);
        ushort* wb7  = (ushort*)(smb + 262144);
        float* bns   = (float*)(smb + 282624);
        float* bnb2  = (float*)(smb + 282880);

        // fused weight prep (1 launch instead of 6)
        wprep<<<(4718592+1179648+294912+73728+10240+64+255)/256, 256, 0, stream>>>(
            w1, w2, w3, w4, c1w, bng, bnb, bnm, bnv,
            wb1, wb2, wb3, wb4, wb7, bns, bnb2);

        // ---- global branch (f32, feeds discrete decisions) ----
        float* gact = nullptr;
        run_stack_f32(x, 8, c1w, bng, bnb, bnm, bnv, w1, w2, w3, w4, GO, &gact, stream);
        row_mean64<float><<<2048,256,0,stream>>>(gact, gmean, 8192);
        head_sigmoid<<<1,256,0,stream>>>(gmean, clsw, clsb, gst, out_gs, 8);
        cam_kernel<<<40,256,0,stream>>>(gact, clsw, clsb, cam, 8);
        resize_cam<<<10240,256,0,stream>>>(cam, out_cs, 8);
        score_maxred<<<160,256,0,stream>>>(out_cs, out_ws, out_hs, 8);
        topk4<<<1,64,0,stream>>>(gst, top, 8);
        gather_norm<<<64,128,0,stream>>>(out_ws, out_hs, top, xs, ysn, 8);
        objloc<<<1,64,0,stream>>>(xs, ysn, box, 8);
        crop_resize_k<<<6144,256,0,stream>>>(x, box, out_li, 8);

        // ---- local branch (bf16 MFMA throughout) ----
        for (int c = 0; c < 2; ++c) {
            im2row7<<<5120,256,0,stream>>>(out_li, BR, c*16, 65536);
            gemm_conv<<<512,256,0,stream>>>(wb7, BR, R1, 64, 160, 65536, 64, 12, c*16, bns, bnb2);
        }
        for (int c = 0; c < 4; ++c) {
            im2row_k<<<9216,256,0,stream>>>(R1, BR, c*8, 32768, 64, 64, 64, 64, 64, 1, 576);
            gemm_conv<<<512,256,0,stream>>>(wb1, BR, R2, 128, 576, 32768, 128, 12, c*8, nullptr, nullptr);
        }
        for (int c = 0; c < 2; ++c) {
            im2row_k<<<9216,256,0,stream>>>(R2, BR, c*16, 16384, 128, 64, 64, 32, 32, 2, 1152);
            gemm_conv<<<512,256,0,stream>>>(wb2, BR, R1, 256, 1152, 16384, 256, 10, c*16, nullptr, nullptr);
        }
        im2row_k<<<9216,256,0,stream>>>(R1, BR, 0, 8192, 256, 32, 32, 16, 16, 2, 2304);
        gemm_conv<<<512,256,0,stream>>>(wb3, BR, R2, 512, 2304, 8192, 512, 8, 0, nullptr, nullptr);
        im2row_k<<<4608,256,0,stream>>>(R2, BR, 0, 2048, 512, 16, 16, 8, 8, 2, 4608);
        gemm_conv<<<256,256,0,stream>>>(wb4, BR, R1, 1024, 4608, 2048, 1024, 6, 0, nullptr, nullptr);

        row_mean64<ushort><<<8192,256,0,stream>>>(R1, lmean, 32768);
        head_sigmoid<<<3,256,0,stream>>>(lmean, clsw, clsb, locf, (float*)nullptr, 32);
        local_stream_max<<<1,256,0,stream>>>(locf, out_ls, 8);
    } else {
        // -------- f32 fallback --------
        char* O = (char*)d_ws;
        char* smb = O + 33554432;
        float* gmean = (float*)(smb);
        float* gst   = (float*)(smb + 32768);
        float* cam   = (float*)(smb + 33408);
        int*   top   = (int*)  (smb + 74368);
        float* xs    = (float*)(smb + 74496);
        float* ysn   = (float*)(smb + 90880);
        int*   box   = (int*)  (smb + 107264);
        float* lmean = (float*)(smb + 107776);
        float* locf  = (float*)(smb + 238848);

        float* act = nullptr;
        run_stack_f32(x, 8, c1w, bng, bnb, bnm, bnv, w1, w2, w3, w4, O, &act, stream);
        row_mean64<float><<<2048,256,0,stream>>>(act, gmean, 8192);
        head_sigmoid<<<1,256,0,stream>>>(gmean, clsw, clsb, gst, out_gs, 8);
        cam_kernel<<<40,256,0,stream>>>(act, clsw, clsb, cam, 8);
        resize_cam<<<10240,256,0,stream>>>(cam, out_cs, 8);
        score_maxred<<<160,256,0,stream>>>(out_cs, out_ws, out_hs, 8);
        topk4<<<1,64,0,stream>>>(gst, top, 8);
        gather_norm<<<64,128,0,stream>>>(out_ws, out_hs, top, xs, ysn, 8);
        objloc<<<1,64,0,stream>>>(xs, ysn, box, 8);
        crop_resize_k<<<6144,256,0,stream>>>(x, box, out_li, 8);

        for (int c = 0; c < 4; ++c) {
            const float* lin_c = out_li + (size_t)c*8*3*16384;
            run_stack_f32(lin_c, 8, c1w, bng, bnb, bnm, bnv, w1, w2, w3, w4, O, &act, stream);
            row_mean64<float><<<2048,256,0,stream>>>(act, lmean + c*8192, 8192);
        }
        head_sigmoid<<<3,256,0,stream>>>(lmean, clsw, clsb, locf, (float*)nullptr, 32);
        local_stream_max<<<1,256,0,stream>>>(locf, out_ls, 8);
    }
}